// Round 10
// baseline (225.696 us; speedup 1.0000x reference)
//
#include <hip/hip_runtime.h>

#define EPSV 1e-5f
#define EB 512            // edge-chunk blocks for counting-sort passes
#define NPB 256           // nodes per bucket (bucket = dst >> 8)
#define NBUK_MAX 512      // supports N up to 131072

typedef unsigned short ushort_t;

// ---- f32 -> bf16 round-to-nearest-even ----
__device__ inline unsigned f2bf(float f){
  unsigned u = __float_as_uint(f);
  u += 0x7fffu + ((u>>16)&1u);
  return u>>16;
}
#define BF_LO(u) __uint_as_float((u)<<16)
#define BF_HI(u) __uint_as_float((u)&0xffff0000u)
__device__ inline float bfu(unsigned short u){ return __uint_as_float(((unsigned)u)<<16); }

// ================= CSR build (two-level counting sort, no global atomics) =================
__global__ __launch_bounds__(256) void k_csr_count(const int* __restrict__ dst, int E, int chunk,
                                                   int nbuk, int* __restrict__ cnt){
  __shared__ int hist[NBUK_MAX];
  int t = threadIdx.x, b = blockIdx.x;
  for(int k=t; k<nbuk; k+=256) hist[k]=0;
  __syncthreads();
  int lo = b*chunk, hi = lo+chunk < E ? lo+chunk : E;
  for(int i=lo+t; i<hi; i+=256) atomicAdd(&hist[dst[i]>>8], 1);
  __syncthreads();
  for(int k=t; k<nbuk; k+=256) cnt[(size_t)k*EB + b] = hist[k];
}

__global__ __launch_bounds__(1024) void k_scan_local(const int* __restrict__ v_in, int L,
                                                     int* __restrict__ loc, int* __restrict__ blk){
  __shared__ int ps[1024];
  int t = threadIdx.x;
  int i = blockIdx.x*1024 + t;
  int v = (i < L) ? v_in[i] : 0;
  ps[t] = v;
  __syncthreads();
  for(int off=1; off<1024; off<<=1){
    int u = (t>=off) ? ps[t-off] : 0;
    __syncthreads();
    ps[t] += u;
    __syncthreads();
  }
  if(i < L) loc[i] = ps[t] - v;
  if(t == 1023) blk[blockIdx.x] = ps[t];
}

__global__ __launch_bounds__(1024) void k_scan_sums(int* __restrict__ blk, int nb,
                                                    int* __restrict__ totalOut){
  __shared__ int ps[1024];
  int t = threadIdx.x;
  int v = (t < nb) ? blk[t] : 0;
  ps[t] = v;
  __syncthreads();
  for(int off=1; off<1024; off<<=1){
    int u = (t>=off) ? ps[t-off] : 0;
    __syncthreads();
    ps[t] += u;
    __syncthreads();
  }
  if(t < nb) blk[t] = ps[t] - v;
  if(t == 1023) *totalOut = ps[t];
}

__global__ __launch_bounds__(256) void k_csr_scatter(const int* __restrict__ src,
                                                     const int* __restrict__ dst,
                                                     const int* __restrict__ loc,
                                                     const int* __restrict__ blk,
                                                     int E, int chunk, int nbuk,
                                                     unsigned* __restrict__ epk){
  __shared__ int cur[NBUK_MAX];
  int t = threadIdx.x, b = blockIdx.x;
  for(int k=t; k<nbuk; k+=256){
    int i = k*EB + b;
    cur[k] = loc[i] + blk[i>>10];
  }
  __syncthreads();
  int lo = b*chunk, hi = lo+chunk < E ? lo+chunk : E;
  for(int i=lo+t; i<hi; i+=256){
    int d = dst[i];
    int p = atomicAdd(&cur[d>>8], 1);
    epk[p] = ((unsigned)src[i]<<8) | (unsigned)(d & 255);
  }
}

__global__ __launch_bounds__(256) void k_csr_final(const unsigned* __restrict__ epk,
                                                   const int* __restrict__ loc,
                                                   const int* __restrict__ blk,
                                                   int nbuk, int N, int E,
                                                   int* __restrict__ rp, float* __restrict__ dis,
                                                   int* __restrict__ csr_src){
  __shared__ int hist[NPB], ps[NPB], cur[NPB];
  int t = threadIdx.x, k = blockIdx.x;
  int i0 = k*EB;
  int base = loc[i0] + blk[i0>>10];
  int next;
  if(k+1 < nbuk){ int i1 = (k+1)*EB; next = loc[i1] + blk[i1>>10]; }
  else next = E;
  int cntk = next - base;
  int node0 = k*NPB;
  hist[t] = 0;
  __syncthreads();
  for(int i=t; i<cntk; i+=256) atomicAdd(&hist[(int)(epk[base+i] & 255u)], 1);
  __syncthreads();
  int deg = hist[t];
  ps[t] = deg;
  __syncthreads();
  for(int off=1; off<256; off<<=1){
    int u = (t>=off) ? ps[t-off] : 0;
    __syncthreads();
    ps[t] += u;
    __syncthreads();
  }
  int lb = ps[t] - deg;
  int n = node0 + t;
  if(n < N){
    rp[n]  = base + lb;
    dis[n] = rsqrtf((float)deg + 1.0f);
  }
  cur[t] = base + lb;
  __syncthreads();
  for(int i=t; i<cntk; i+=256){
    unsigned e = epk[base+i];
    int p = atomicAdd(&cur[(int)(e & 255u)], 1);
    csr_src[p] = (int)(e >> 8);
  }
  if(k == nbuk-1 && t == 0) rp[N] = E;
}

// ================= layer-1 GEMM (f32 VALU): P1 = bf16((x @ W1) * dis[row]) =================
__global__ __launch_bounds__(256) void k_gemm1(const float* __restrict__ x,
                                               const float* __restrict__ W,
                                               const float* __restrict__ dis,
                                               int N, ushort_t* __restrict__ P1){
  __shared__ __align__(16) float Ws[32*16];
  int t = threadIdx.x;
  for(int i=t; i<32*16; i+=256) Ws[i] = W[i];
  __syncthreads();
  int row = blockIdx.x*256 + t;
  if(row >= N) return;
  const float4* xr = (const float4*)(x + (size_t)row*32);
  float acc[16];
  #pragma unroll
  for(int j=0;j<16;j++) acc[j]=0.f;
  #pragma unroll
  for(int k4=0;k4<8;k4++){
    float4 v = xr[k4];
    float vv[4] = {v.x, v.y, v.z, v.w};
    #pragma unroll
    for(int kk=0;kk<4;kk++){
      float h = vv[kk];
      const float* wr = &Ws[(k4*4+kk)*16];
      #pragma unroll
      for(int j=0;j<16;j++) acc[j] += h*wr[j];
    }
  }
  float d = dis[row];
  unsigned q[8];
  #pragma unroll
  for(int j=0;j<8;j++)
    q[j] = f2bf(acc[2*j]*d) | (f2bf(acc[2*j+1]*d)<<16);
  uint4* o = (uint4*)(P1 + (size_t)row*16);
  o[0] = make_uint4(q[0],q[1],q[2],q[3]);
  o[1] = make_uint4(q[4],q[5],q[6],q[7]);
}

// ================= layer-1 gather: h1 = tanh(dis*(P1[n]+sum P1[s]) + b1) =================
// writes Q1 = bf16(h1 * dis), sdis[n] = sum dis[s], BN stats over h1
__global__ __launch_bounds__(256) void k_gather1(const int* __restrict__ rp,
    const int* __restrict__ csr_src,
    const float* __restrict__ dis, const ushort_t* __restrict__ P1,
    const float* __restrict__ bias, int N, ushort_t* __restrict__ Q1,
    float* __restrict__ sdis, float* __restrict__ partials){
  int t = threadIdx.x;
  int idx = blockIdx.x*256 + t;
  int n = idx >> 1, g = t & 1;
  float v[8];
  #pragma unroll
  for(int j=0;j<8;j++) v[j]=0.f;

  if(n < N){
    int beg = rp[n], end = rp[n+1];
    uint4 u = *(const uint4*)(P1 + (size_t)n*16 + g*8);
    float a0 = BF_LO(u.x), a1 = BF_HI(u.x), a2 = BF_LO(u.y), a3 = BF_HI(u.y);
    float a4 = BF_LO(u.z), a5 = BF_HI(u.z), a6 = BF_LO(u.w), a7 = BF_HI(u.w);
    float b0=0.f,b1=0.f,b2=0.f,b3=0.f,b4=0.f,b5=0.f,b6=0.f,b7=0.f;
    float sd = 0.f;
    int j = beg;
    for(; j+1 < end; j += 2){
      int s0 = csr_src[j], s1 = csr_src[j+1];
      uint4 u0 = *(const uint4*)(P1 + (size_t)s0*16 + g*8);
      uint4 u1 = *(const uint4*)(P1 + (size_t)s1*16 + g*8);
      if(g==0) sd += dis[s0] + dis[s1];
      a0 += BF_LO(u0.x); a1 += BF_HI(u0.x); a2 += BF_LO(u0.y); a3 += BF_HI(u0.y);
      a4 += BF_LO(u0.z); a5 += BF_HI(u0.z); a6 += BF_LO(u0.w); a7 += BF_HI(u0.w);
      b0 += BF_LO(u1.x); b1 += BF_HI(u1.x); b2 += BF_LO(u1.y); b3 += BF_HI(u1.y);
      b4 += BF_LO(u1.z); b5 += BF_HI(u1.z); b6 += BF_LO(u1.w); b7 += BF_HI(u1.w);
    }
    if(j < end){
      int s0 = csr_src[j];
      uint4 u0 = *(const uint4*)(P1 + (size_t)s0*16 + g*8);
      if(g==0) sd += dis[s0];
      a0 += BF_LO(u0.x); a1 += BF_HI(u0.x); a2 += BF_LO(u0.y); a3 += BF_HI(u0.y);
      a4 += BF_LO(u0.z); a5 += BF_HI(u0.z); a6 += BF_LO(u0.w); a7 += BF_HI(u0.w);
    }
    float d = dis[n];
    float4 bb0 = *(const float4*)(bias + g*8);
    float4 bb1 = *(const float4*)(bias + g*8 + 4);
    v[0] = tanhf((a0+b0)*d + bb0.x); v[1] = tanhf((a1+b1)*d + bb0.y);
    v[2] = tanhf((a2+b2)*d + bb0.z); v[3] = tanhf((a3+b3)*d + bb0.w);
    v[4] = tanhf((a4+b4)*d + bb1.x); v[5] = tanhf((a5+b5)*d + bb1.y);
    v[6] = tanhf((a6+b6)*d + bb1.z); v[7] = tanhf((a7+b7)*d + bb1.w);
    uint4 o;
    o.x = f2bf(v[0]*d) | (f2bf(v[1]*d)<<16);
    o.y = f2bf(v[2]*d) | (f2bf(v[3]*d)<<16);
    o.z = f2bf(v[4]*d) | (f2bf(v[5]*d)<<16);
    o.w = f2bf(v[6]*d) | (f2bf(v[7]*d)<<16);
    *(uint4*)(Q1 + (size_t)n*16 + g*8) = o;
    if(g==0) sdis[n] = sd;
  }

  // BN stats over h1 (v), C=16, GP=2
  int lane = t & 63, wid = t >> 6;
  __shared__ float redS[4][2][8], redQ[4][2][8];
  #pragma unroll
  for(int j=0;j<8;j++){
    float s = v[j], q = v[j]*v[j];
    #pragma unroll
    for(int off=32; off>=2; off>>=1){
      s += __shfl_down(s, off, 64);
      q += __shfl_down(q, off, 64);
    }
    if(lane < 2){ redS[wid][lane][j] = s; redQ[wid][lane][j] = q; }
  }
  __syncthreads();
  if(t < 16){
    int gg = t>>3, j = t&7;
    float S = redS[0][gg][j]+redS[1][gg][j]+redS[2][gg][j]+redS[3][gg][j];
    float Q = redQ[0][gg][j]+redQ[1][gg][j]+redQ[2][gg][j]+redQ[3][gg][j];
    partials[(size_t)blockIdx.x*32 + t]      = S;
    partials[(size_t)blockIdx.x*32 + 16 + t] = Q;
  }
}

// ================= BN reduce stage 1 =================
template<int C>
__global__ __launch_bounds__(256) void k_bn_red(const float* __restrict__ partials, int nblk,
                                                float* __restrict__ red){
  constexpr int W = 2*C;
  constexpr int RPF = 256/W;
  int t = threadIdx.x;
  int c = t % W, r0 = t / W;
  float acc = 0.f;
  for(int r = blockIdx.x*RPF + r0; r < nblk; r += 64*RPF)
    acc += partials[(size_t)r*W + c];
  __shared__ float ls[256];
  ls[t] = acc;
  __syncthreads();
  if(t < W){
    float s = 0.f;
    #pragma unroll
    for(int k=0;k<RPF;k++) s += ls[k*W + t];
    red[blockIdx.x*W + t] = s;
  }
}

// ================= BN finalize + plain f32 weight prep: Wp = sc.*W, cp = sh @ W =================
template<int C>
__global__ __launch_bounds__(256) void k_bn_finprep2(const float* __restrict__ red,
                           const float* __restrict__ gw, const float* __restrict__ be,
                           float invN, const float* __restrict__ W,
                           float* __restrict__ Wp, float* __restrict__ cp){
  __shared__ float s0[C], s1[C], scf[C], shf[C];
  int t = threadIdx.x;
  if(t < 2*C){
    float s = 0.f;
    for(int r=0;r<64;r++) s += red[r*2*C + t];
    if(t < C) s0[t] = s; else s1[t-C] = s;
  }
  __syncthreads();
  if(t < C){
    float m = s0[t]*invN;
    float var = fmaxf(s1[t]*invN - m*m, 0.f);
    float inv = rsqrtf(var + EPSV);
    float sc = gw[t]*inv;
    scf[t] = sc;
    shf[t] = be[t] - m*sc;
  }
  __syncthreads();
  for(int i=t; i<C*64; i+=256){
    int k = i >> 6;
    Wp[i] = scf[k]*W[i];
  }
  if(t < 64){
    float s = 0.f;
    for(int k=0;k<C;k++) s += shf[k]*W[k*64 + t];
    cp[t] = s;
  }
}

// ================= layer-2 fused: gather Q1 (16-wide) + VALU GEMM + tanh + stats =================
// h2 = tanh(dis_n*(M@W2' + sigma*c2') + b2),  M = Q1[n]+sum Q1[s],  sigma = sdis[n]+dis[n]
// writes Q2 = bf16(h2*dis_n); 8 lanes/node, 4-way edge interleave
__global__ __launch_bounds__(256) void k_l2fused(const int* __restrict__ rp,
    const int* __restrict__ csr_src, const float* __restrict__ dis,
    const float* __restrict__ sdis, const ushort_t* __restrict__ Q1,
    const float* __restrict__ Wp, const float* __restrict__ cp,
    const float* __restrict__ bias, int N, ushort_t* __restrict__ Q2,
    float* __restrict__ partials){
  __shared__ __align__(16) float Wl[16*64];
  __shared__ float cpl[64], bl[64];
  int t = threadIdx.x;
  for(int i=t; i<16*64; i+=256) Wl[i] = Wp[i];
  if(t < 64){ cpl[t] = cp[t]; bl[t] = bias[t]; }
  __syncthreads();

  int idx = blockIdx.x*256 + t;
  int n = idx >> 3, g = t & 7;
  int half = g & 1, eo = g >> 1;
  bool valid = (n < N);
  float M8[8];
  #pragma unroll
  for(int j=0;j<8;j++) M8[j]=0.f;

  if(valid){
    int beg = rp[n], end = rp[n+1];
    if(eo == 0){
      uint4 u = *(const uint4*)(Q1 + (size_t)n*16 + half*8);
      M8[0]+=BF_LO(u.x); M8[1]+=BF_HI(u.x); M8[2]+=BF_LO(u.y); M8[3]+=BF_HI(u.y);
      M8[4]+=BF_LO(u.z); M8[5]+=BF_HI(u.z); M8[6]+=BF_LO(u.w); M8[7]+=BF_HI(u.w);
    }
    for(int j=beg+eo; j<end; j+=4){
      int s = csr_src[j];
      uint4 u = *(const uint4*)(Q1 + (size_t)s*16 + half*8);
      M8[0]+=BF_LO(u.x); M8[1]+=BF_HI(u.x); M8[2]+=BF_LO(u.y); M8[3]+=BF_HI(u.y);
      M8[4]+=BF_LO(u.z); M8[5]+=BF_HI(u.z); M8[6]+=BF_LO(u.w); M8[7]+=BF_HI(u.w);
    }
  }
  // combine across the 4 edge-offset lanes (lane bits 1,2)
  #pragma unroll
  for(int j=0;j<8;j++){
    float m = M8[j];
    m += __shfl_xor(m, 2, 64);
    m += __shfl_xor(m, 4, 64);
    M8[j] = m;
  }
  // assemble full M[16] (exchange halves, lane bit 0)
  float M16[16];
  #pragma unroll
  for(int j=0;j<8;j++){
    float o = __shfl_xor(M8[j], 1, 64);
    M16[j]   = (half==0) ? M8[j] : o;
    M16[8+j] = (half==0) ? o     : M8[j];
  }

  float v[8];
  #pragma unroll
  for(int j=0;j<8;j++) v[j]=0.f;
  if(valid){
    float d = dis[n];
    float sg = sdis[n] + d;
    int c0 = g*8;
    float acc[8];
    #pragma unroll
    for(int j=0;j<8;j++) acc[j] = cpl[c0+j]*sg;
    #pragma unroll
    for(int k=0;k<16;k++){
      float m = M16[k];
      float4 w0 = *(const float4*)&Wl[k*64 + c0];
      float4 w1 = *(const float4*)&Wl[k*64 + c0 + 4];
      acc[0]+=m*w0.x; acc[1]+=m*w0.y; acc[2]+=m*w0.z; acc[3]+=m*w0.w;
      acc[4]+=m*w1.x; acc[5]+=m*w1.y; acc[6]+=m*w1.z; acc[7]+=m*w1.w;
    }
    #pragma unroll
    for(int j=0;j<8;j++) v[j] = tanhf(d*acc[j] + bl[c0+j]);
    uint4 o;
    o.x = f2bf(v[0]*d) | (f2bf(v[1]*d)<<16);
    o.y = f2bf(v[2]*d) | (f2bf(v[3]*d)<<16);
    o.z = f2bf(v[4]*d) | (f2bf(v[5]*d)<<16);
    o.w = f2bf(v[6]*d) | (f2bf(v[7]*d)<<16);
    *(uint4*)(Q2 + (size_t)n*64 + c0) = o;
  }

  // BN stats over h2 (v), C=64, GP=8
  int lane = t & 63, wid = t >> 6;
  __shared__ float redS[4][8][8], redQ[4][8][8];
  #pragma unroll
  for(int j=0;j<8;j++){
    float s = v[j], q = v[j]*v[j];
    #pragma unroll
    for(int off=32; off>=8; off>>=1){
      s += __shfl_down(s, off, 64);
      q += __shfl_down(q, off, 64);
    }
    if(lane < 8){ redS[wid][lane][j] = s; redQ[wid][lane][j] = q; }
  }
  __syncthreads();
  if(t < 64){
    int gg = t>>3, j = t&7;
    float S = redS[0][gg][j]+redS[1][gg][j]+redS[2][gg][j]+redS[3][gg][j];
    float Q = redQ[0][gg][j]+redQ[1][gg][j]+redQ[2][gg][j]+redQ[3][gg][j];
    partials[(size_t)blockIdx.x*128 + t]      = S;
    partials[(size_t)blockIdx.x*128 + 64 + t] = Q;
  }
}

// ================= layer-3 fused: gather Q2 (64-wide) + VALU GEMM + tanh =================
// h3 = tanh(dis_n*(M@W3' + sigma*c3') + b3), writes H3 bf16
__global__ __launch_bounds__(256) void k_l3fused(const int* __restrict__ rp,
    const int* __restrict__ csr_src, const float* __restrict__ dis,
    const float* __restrict__ sdis, const ushort_t* __restrict__ Q2,
    const float* __restrict__ Wp, const float* __restrict__ cp,
    const float* __restrict__ bias, int N, ushort_t* __restrict__ H3){
  __shared__ __align__(16) float Wl[64*64];
  __shared__ float cpl[64], bl[64];
  __shared__ float Ml[32][68];       // padded to avoid bank conflicts
  int t = threadIdx.x;
  for(int i=t; i<64*64; i+=256) Wl[i] = Wp[i];
  if(t < 64){ cpl[t] = cp[t]; bl[t] = bias[t]; }
  __syncthreads();

  int idx = blockIdx.x*256 + t;
  int n = idx >> 3, g = t & 7;
  int nl = t >> 3;
  bool valid = (n < N);
  float a0=0.f,a1=0.f,a2=0.f,a3=0.f,a4=0.f,a5=0.f,a6=0.f,a7=0.f;
  float b0=0.f,b1=0.f,b2=0.f,b3=0.f,b4=0.f,b5=0.f,b6=0.f,b7=0.f;

  if(valid){
    int beg = rp[n], end = rp[n+1];
    uint4 u = *(const uint4*)(Q2 + (size_t)n*64 + g*8);   // self
    a0 += BF_LO(u.x); a1 += BF_HI(u.x); a2 += BF_LO(u.y); a3 += BF_HI(u.y);
    a4 += BF_LO(u.z); a5 += BF_HI(u.z); a6 += BF_LO(u.w); a7 += BF_HI(u.w);
    int j = beg;
    for(; j+1 < end; j += 2){
      int s0 = csr_src[j], s1 = csr_src[j+1];
      uint4 u0 = *(const uint4*)(Q2 + (size_t)s0*64 + g*8);
      uint4 u1 = *(const uint4*)(Q2 + (size_t)s1*64 + g*8);
      a0 += BF_LO(u0.x); a1 += BF_HI(u0.x); a2 += BF_LO(u0.y); a3 += BF_HI(u0.y);
      a4 += BF_LO(u0.z); a5 += BF_HI(u0.z); a6 += BF_LO(u0.w); a7 += BF_HI(u0.w);
      b0 += BF_LO(u1.x); b1 += BF_HI(u1.x); b2 += BF_LO(u1.y); b3 += BF_HI(u1.y);
      b4 += BF_LO(u1.z); b5 += BF_HI(u1.z); b6 += BF_LO(u1.w); b7 += BF_HI(u1.w);
    }
    if(j < end){
      int s0 = csr_src[j];
      uint4 u0 = *(const uint4*)(Q2 + (size_t)s0*64 + g*8);
      a0 += BF_LO(u0.x); a1 += BF_HI(u0.x); a2 += BF_LO(u0.y); a3 += BF_HI(u0.y);
      a4 += BF_LO(u0.z); a5 += BF_HI(u0.z); a6 += BF_LO(u0.w); a7 += BF_HI(u0.w);
    }
  }
  int c0 = g*8;
  Ml[nl][c0+0]=a0+b0; Ml[nl][c0+1]=a1+b1; Ml[nl][c0+2]=a2+b2; Ml[nl][c0+3]=a3+b3;
  Ml[nl][c0+4]=a4+b4; Ml[nl][c0+5]=a5+b5; Ml[nl][c0+6]=a6+b6; Ml[nl][c0+7]=a7+b7;
  __syncthreads();

  if(valid){
    float d = dis[n];
    float sg = sdis[n] + d;
    float acc[8];
    #pragma unroll
    for(int j=0;j<8;j++) acc[j] = cpl[c0+j]*sg;
    #pragma unroll 8
    for(int k=0;k<64;k++){
      float m = Ml[nl][k];
      float4 w0 = *(const float4*)&Wl[k*64 + c0];
      float4 w1 = *(const float4*)&Wl[k*64 + c0 + 4];
      acc[0]+=m*w0.x; acc[1]+=m*w0.y; acc[2]+=m*w0.z; acc[3]+=m*w0.w;
      acc[4]+=m*w1.x; acc[5]+=m*w1.y; acc[6]+=m*w1.z; acc[7]+=m*w1.w;
    }
    float v[8];
    #pragma unroll
    for(int j=0;j<8;j++) v[j] = tanhf(d*acc[j] + bl[c0+j]);
    uint4 o;
    o.x = f2bf(v[0]) | (f2bf(v[1])<<16);
    o.y = f2bf(v[2]) | (f2bf(v[3])<<16);
    o.z = f2bf(v[4]) | (f2bf(v[5])<<16);
    o.w = f2bf(v[6]) | (f2bf(v[7])<<16);
    *(uint4*)(H3 + (size_t)n*64 + c0) = o;
  }
}

// ================= mean-pool per graph + linear head =================
__global__ __launch_bounds__(256) void k_pool(const ushort_t* __restrict__ H3,
                                              const int* __restrict__ batch, int N,
                                              const float* __restrict__ Wc,
                                              const float* __restrict__ bc,
                                              float* __restrict__ out){
  int gId = blockIdx.x;
  int t = threadIdx.x;
  int lo=0, hi=N;
  while(lo<hi){ int mid=(lo+hi)>>1; if(batch[mid] < gId) lo=mid+1; else hi=mid; }
  int start = lo;
  lo=start; hi=N;
  while(lo<hi){ int mid=(lo+hi)>>1; if(batch[mid] < gId+1) lo=mid+1; else hi=mid; }
  int end = lo;

  int c = t & 63, rg = t >> 6;
  float s = 0.f;
  for(int r = start+rg; r < end; r += 4) s += bfu(H3[(size_t)r*64 + c]);
  __shared__ float ls[256];
  ls[t] = s;
  __syncthreads();
  if(t < 64){
    float tot = ls[t] + ls[64+t] + ls[128+t] + ls[192+t];
    float cnt = (float)(end - start);
    float mean = tot / fmaxf(cnt, 1.0f);
    float v = mean * Wc[t];
    #pragma unroll
    for(int o=32; o>0; o>>=1) v += __shfl_down(v, o, 64);
    if(t == 0) out[gId] = v + bc[0];
  }
}

// ================= host launch =================
extern "C" void kernel_launch(void* const* d_in, const int* in_sizes, int n_in,
                              void* d_out, int out_size, void* d_ws, size_t ws_size,
                              hipStream_t stream) {
  const float* x     = (const float*)d_in[0];
  const int*   ei    = (const int*)d_in[1];
  const int*   batch = (const int*)d_in[2];
  const float* W1 = (const float*)d_in[3];
  const float* b1 = (const float*)d_in[4];
  const float* g1 = (const float*)d_in[5];
  const float* be1= (const float*)d_in[6];
  const float* W2 = (const float*)d_in[7];
  const float* b2 = (const float*)d_in[8];
  const float* g2 = (const float*)d_in[9];
  const float* be2= (const float*)d_in[10];
  const float* W3 = (const float*)d_in[11];
  const float* b3 = (const float*)d_in[12];
  const float* Wc = (const float*)d_in[13];
  const float* bc = (const float*)d_in[14];

  int N = in_sizes[2];
  int E = in_sizes[1] / 2;
  int G = out_size;
  const int* srcp = ei;
  const int* dstp = ei + E;
  float* out = (float*)d_out;

  auto cdiv = [](long long a, long long b){ return (int)((a+b-1)/b); };
  auto al16 = [](size_t s){ return (s + 15) & ~(size_t)15; };
  int nbuk  = cdiv(N, NPB);
  int chunk = cdiv(E, EB);
  int L     = nbuk * EB;
  int nbL   = cdiv(L, 1024);
  int nblk16 = cdiv((long long)N*2, 256);
  int nblk64 = cdiv((long long)N*8, 256);

  char* w = (char*)d_ws;
  ushort_t* Q1       = (ushort_t*)w; w += al16((size_t)N*16*2);
  ushort_t* P1       = (ushort_t*)w; w += al16((size_t)N*16*2);
  ushort_t* Q2       = (ushort_t*)w; w += al16((size_t)N*64*2);
  ushort_t* H3       = (ushort_t*)w; w += al16((size_t)N*64*2);
  float*    dis      = (float*)w;    w += al16((size_t)N*4);
  float*    sdis     = (float*)w;    w += al16((size_t)N*4);
  int*      row_ptr  = (int*)w;      w += al16((size_t)(N+1)*4);
  int*      csr_src  = (int*)w;      w += al16((size_t)E*4);
  unsigned* epk      = (unsigned*)w; w += al16((size_t)E*4);
  int*      cnt      = (int*)w;      w += al16((size_t)L*4);
  int*      scan_loc = (int*)w;      w += al16((size_t)L*4);
  int*      scan_blk = (int*)w;      w += al16(1024*4);
  float*    partials = (float*)w;    w += al16((size_t)nblk64*128*4);
  float*    red      = (float*)w;    w += al16(64*128*4);
  float*    Wp       = (float*)w;    w += al16(64*64*4);
  float*    cp       = (float*)w;    w += al16(64*4);

  // ---- CSR build ----
  k_csr_count<<<EB,256,0,stream>>>(dstp, E, chunk, nbuk, cnt);
  k_scan_local<<<nbL,1024,0,stream>>>(cnt, L, scan_loc, scan_blk);
  k_scan_sums<<<1,1024,0,stream>>>(scan_blk, nbL, row_ptr + N);
  k_csr_scatter<<<EB,256,0,stream>>>(srcp, dstp, scan_loc, scan_blk, E, chunk, nbuk, epk);
  k_csr_final<<<nbuk,256,0,stream>>>(epk, scan_loc, scan_blk, nbuk, N, E, row_ptr, dis, csr_src);

  // ---- Layer 1: 32 -> 16 ----
  k_gemm1<<<cdiv(N,256),256,0,stream>>>(x, W1, dis, N, P1);
  k_gather1<<<nblk16,256,0,stream>>>(row_ptr, csr_src, dis, P1, b1, N, Q1, sdis, partials);
  k_bn_red<16><<<64,256,0,stream>>>(partials, nblk16, red);
  k_bn_finprep2<16><<<1,256,0,stream>>>(red, g1, be1, 1.0f/N, W2, Wp, cp);

  // ---- Layer 2: fused gather(16-wide) + GEMM + stats ----
  k_l2fused<<<nblk64,256,0,stream>>>(row_ptr, csr_src, dis, sdis, Q1, Wp, cp, b2, N, Q2, partials);
  k_bn_red<64><<<64,256,0,stream>>>(partials, nblk64, red);
  k_bn_finprep2<64><<<1,256,0,stream>>>(red, g2, be2, 1.0f/N, W3, Wp, cp);

  // ---- Layer 3: fused gather(64-wide) + GEMM ----
  k_l3fused<<<nblk64,256,0,stream>>>(row_ptr, csr_src, dis, sdis, Q2, Wp, cp, b3, N, H3);

  // ---- Pool + head ----
  k_pool<<<G,256,0,stream>>>(H3, batch, N, Wc, bc, out);
}

// Round 11
// 201.984 us; speedup vs baseline: 1.1174x; 1.1174x over previous
//
#include <hip/hip_runtime.h>

#define EPSV 1e-5f
#define EB 512            // edge-chunk blocks for counting-sort passes
#define NPB 256           // nodes per bucket (bucket = dst >> 8)
#define NBUK_MAX 512      // supports N up to 131072

typedef __attribute__((ext_vector_type(8))) short bf16x8;
typedef __attribute__((ext_vector_type(4))) float f32x4;
typedef unsigned short ushort_t;

// ---- f32 -> bf16 round-to-nearest-even ----
__device__ inline unsigned f2bf(float f){
  unsigned u = __float_as_uint(f);
  u += 0x7fffu + ((u>>16)&1u);
  return u>>16;
}
#define BF_LO(u) __uint_as_float((u)<<16)
#define BF_HI(u) __uint_as_float((u)&0xffff0000u)

// ================= CSR build (two-level counting sort, no global atomics) =================
__global__ __launch_bounds__(256) void k_csr_count(const int* __restrict__ dst, int E, int chunk,
                                                   int nbuk, int* __restrict__ cnt){
  __shared__ int hist[NBUK_MAX];
  int t = threadIdx.x, b = blockIdx.x;
  for(int k=t; k<nbuk; k+=256) hist[k]=0;
  __syncthreads();
  int lo = b*chunk, hi = lo+chunk < E ? lo+chunk : E;
  for(int i=lo+t; i<hi; i+=256) atomicAdd(&hist[dst[i]>>8], 1);
  __syncthreads();
  for(int k=t; k<nbuk; k+=256) cnt[(size_t)k*EB + b] = hist[k];
}

__global__ __launch_bounds__(1024) void k_scan_local(const int* __restrict__ v_in, int L,
                                                     int* __restrict__ loc, int* __restrict__ blk){
  __shared__ int ps[1024];
  int t = threadIdx.x;
  int i = blockIdx.x*1024 + t;
  int v = (i < L) ? v_in[i] : 0;
  ps[t] = v;
  __syncthreads();
  for(int off=1; off<1024; off<<=1){
    int u = (t>=off) ? ps[t-off] : 0;
    __syncthreads();
    ps[t] += u;
    __syncthreads();
  }
  if(i < L) loc[i] = ps[t] - v;
  if(t == 1023) blk[blockIdx.x] = ps[t];
}

__global__ __launch_bounds__(1024) void k_scan_sums(int* __restrict__ blk, int nb,
                                                    int* __restrict__ totalOut){
  __shared__ int ps[1024];
  int t = threadIdx.x;
  int v = (t < nb) ? blk[t] : 0;
  ps[t] = v;
  __syncthreads();
  for(int off=1; off<1024; off<<=1){
    int u = (t>=off) ? ps[t-off] : 0;
    __syncthreads();
    ps[t] += u;
    __syncthreads();
  }
  if(t < nb) blk[t] = ps[t] - v;
  if(t == 1023) *totalOut = ps[t];
}

__global__ __launch_bounds__(256) void k_csr_scatter(const int* __restrict__ src,
                                                     const int* __restrict__ dst,
                                                     const int* __restrict__ loc,
                                                     const int* __restrict__ blk,
                                                     int E, int chunk, int nbuk,
                                                     unsigned* __restrict__ epk){
  __shared__ int cur[NBUK_MAX];
  int t = threadIdx.x, b = blockIdx.x;
  for(int k=t; k<nbuk; k+=256){
    int i = k*EB + b;
    cur[k] = loc[i] + blk[i>>10];
  }
  __syncthreads();
  int lo = b*chunk, hi = lo+chunk < E ? lo+chunk : E;
  for(int i=lo+t; i<hi; i+=256){
    int d = dst[i];
    int p = atomicAdd(&cur[d>>8], 1);
    epk[p] = ((unsigned)src[i]<<8) | (unsigned)(d & 255);
  }
}

__global__ __launch_bounds__(256) void k_csr_final(const unsigned* __restrict__ epk,
                                                   const int* __restrict__ loc,
                                                   const int* __restrict__ blk,
                                                   int nbuk, int N, int E,
                                                   int* __restrict__ rp, float* __restrict__ dis,
                                                   int* __restrict__ csr_src){
  __shared__ int hist[NPB], ps[NPB], cur[NPB];
  int t = threadIdx.x, k = blockIdx.x;
  int i0 = k*EB;
  int base = loc[i0] + blk[i0>>10];
  int next;
  if(k+1 < nbuk){ int i1 = (k+1)*EB; next = loc[i1] + blk[i1>>10]; }
  else next = E;
  int cntk = next - base;
  int node0 = k*NPB;
  hist[t] = 0;
  __syncthreads();
  for(int i=t; i<cntk; i+=256) atomicAdd(&hist[(int)(epk[base+i] & 255u)], 1);
  __syncthreads();
  int deg = hist[t];
  ps[t] = deg;
  __syncthreads();
  for(int off=1; off<256; off<<=1){
    int u = (t>=off) ? ps[t-off] : 0;
    __syncthreads();
    ps[t] += u;
    __syncthreads();
  }
  int lb = ps[t] - deg;
  int n = node0 + t;
  if(n < N){
    rp[n]  = base + lb;
    dis[n] = rsqrtf((float)deg + 1.0f);
  }
  cur[t] = base + lb;
  __syncthreads();
  for(int i=t; i<cntk; i+=256){
    unsigned e = epk[base+i];
    int p = atomicAdd(&cur[(int)(e & 255u)], 1);
    csr_src[p] = (int)(e >> 8);
  }
  if(k == nbuk-1 && t == 0) rp[N] = E;
}

// ================= layer-1 GEMM (f32 VALU): P1 = bf16((x @ W1) * dis[row]) =================
__global__ __launch_bounds__(256) void k_gemm1(const float* __restrict__ x,
                                               const float* __restrict__ W,
                                               const float* __restrict__ dis,
                                               int N, ushort_t* __restrict__ P1){
  __shared__ __align__(16) float Ws[32*16];
  int t = threadIdx.x;
  for(int i=t; i<32*16; i+=256) Ws[i] = W[i];
  __syncthreads();
  int row = blockIdx.x*256 + t;
  if(row >= N) return;
  const float4* xr = (const float4*)(x + (size_t)row*32);
  float acc[16];
  #pragma unroll
  for(int j=0;j<16;j++) acc[j]=0.f;
  #pragma unroll
  for(int k4=0;k4<8;k4++){
    float4 v = xr[k4];
    float vv[4] = {v.x, v.y, v.z, v.w};
    #pragma unroll
    for(int kk=0;kk<4;kk++){
      float h = vv[kk];
      const float* wr = &Ws[(k4*4+kk)*16];
      #pragma unroll
      for(int j=0;j<16;j++) acc[j] += h*wr[j];
    }
  }
  float d = dis[row];
  unsigned q[8];
  #pragma unroll
  for(int j=0;j<8;j++)
    q[j] = f2bf(acc[2*j]*d) | (f2bf(acc[2*j+1]*d)<<16);
  uint4* o = (uint4*)(P1 + (size_t)row*16);
  o[0] = make_uint4(q[0],q[1],q[2],q[3]);
  o[1] = make_uint4(q[4],q[5],q[6],q[7]);
}

// ================= layer-1 gather: h1 = tanh(dis*(P1[n]+sum P1[s]) + b1) =================
// writes Q1 = bf16(h1 * dis), sdis[n] = sum dis[s], BN stats over h1
__global__ __launch_bounds__(256) void k_gather1(const int* __restrict__ rp,
    const int* __restrict__ csr_src,
    const float* __restrict__ dis, const ushort_t* __restrict__ P1,
    const float* __restrict__ bias, int N, ushort_t* __restrict__ Q1,
    float* __restrict__ sdis, float* __restrict__ partials){
  int t = threadIdx.x;
  int idx = blockIdx.x*256 + t;
  int n = idx >> 1, g = t & 1;
  float v[8];
  #pragma unroll
  for(int j=0;j<8;j++) v[j]=0.f;

  if(n < N){
    int beg = rp[n], end = rp[n+1];
    uint4 u = *(const uint4*)(P1 + (size_t)n*16 + g*8);
    float a0 = BF_LO(u.x), a1 = BF_HI(u.x), a2 = BF_LO(u.y), a3 = BF_HI(u.y);
    float a4 = BF_LO(u.z), a5 = BF_HI(u.z), a6 = BF_LO(u.w), a7 = BF_HI(u.w);
    float b0=0.f,b1=0.f,b2=0.f,b3=0.f,b4=0.f,b5=0.f,b6=0.f,b7=0.f;
    float sd = 0.f;
    int j = beg;
    for(; j+1 < end; j += 2){
      int s0 = csr_src[j], s1 = csr_src[j+1];
      uint4 u0 = *(const uint4*)(P1 + (size_t)s0*16 + g*8);
      uint4 u1 = *(const uint4*)(P1 + (size_t)s1*16 + g*8);
      if(g==0) sd += dis[s0] + dis[s1];
      a0 += BF_LO(u0.x); a1 += BF_HI(u0.x); a2 += BF_LO(u0.y); a3 += BF_HI(u0.y);
      a4 += BF_LO(u0.z); a5 += BF_HI(u0.z); a6 += BF_LO(u0.w); a7 += BF_HI(u0.w);
      b0 += BF_LO(u1.x); b1 += BF_HI(u1.x); b2 += BF_LO(u1.y); b3 += BF_HI(u1.y);
      b4 += BF_LO(u1.z); b5 += BF_HI(u1.z); b6 += BF_LO(u1.w); b7 += BF_HI(u1.w);
    }
    if(j < end){
      int s0 = csr_src[j];
      uint4 u0 = *(const uint4*)(P1 + (size_t)s0*16 + g*8);
      if(g==0) sd += dis[s0];
      a0 += BF_LO(u0.x); a1 += BF_HI(u0.x); a2 += BF_LO(u0.y); a3 += BF_HI(u0.y);
      a4 += BF_LO(u0.z); a5 += BF_HI(u0.z); a6 += BF_LO(u0.w); a7 += BF_HI(u0.w);
    }
    float d = dis[n];
    float4 bb0 = *(const float4*)(bias + g*8);
    float4 bb1 = *(const float4*)(bias + g*8 + 4);
    v[0] = tanhf((a0+b0)*d + bb0.x); v[1] = tanhf((a1+b1)*d + bb0.y);
    v[2] = tanhf((a2+b2)*d + bb0.z); v[3] = tanhf((a3+b3)*d + bb0.w);
    v[4] = tanhf((a4+b4)*d + bb1.x); v[5] = tanhf((a5+b5)*d + bb1.y);
    v[6] = tanhf((a6+b6)*d + bb1.z); v[7] = tanhf((a7+b7)*d + bb1.w);
    uint4 o;
    o.x = f2bf(v[0]*d) | (f2bf(v[1]*d)<<16);
    o.y = f2bf(v[2]*d) | (f2bf(v[3]*d)<<16);
    o.z = f2bf(v[4]*d) | (f2bf(v[5]*d)<<16);
    o.w = f2bf(v[6]*d) | (f2bf(v[7]*d)<<16);
    *(uint4*)(Q1 + (size_t)n*16 + g*8) = o;
    if(g==0) sdis[n] = sd;
  }

  // BN stats over h1 (v), C=16, GP=2
  int lane = t & 63, wid = t >> 6;
  __shared__ float redS[4][2][8], redQ[4][2][8];
  #pragma unroll
  for(int j=0;j<8;j++){
    float s = v[j], q = v[j]*v[j];
    #pragma unroll
    for(int off=32; off>=2; off>>=1){
      s += __shfl_down(s, off, 64);
      q += __shfl_down(q, off, 64);
    }
    if(lane < 2){ redS[wid][lane][j] = s; redQ[wid][lane][j] = q; }
  }
  __syncthreads();
  if(t < 16){
    int gg = t>>3, j = t&7;
    float S = redS[0][gg][j]+redS[1][gg][j]+redS[2][gg][j]+redS[3][gg][j];
    float Q = redQ[0][gg][j]+redQ[1][gg][j]+redQ[2][gg][j]+redQ[3][gg][j];
    partials[(size_t)blockIdx.x*32 + t]      = S;
    partials[(size_t)blockIdx.x*32 + 16 + t] = Q;
  }
}

// ================= BN reduce stage 1 =================
template<int C>
__global__ __launch_bounds__(256) void k_bn_red(const float* __restrict__ partials, int nblk,
                                                float* __restrict__ red){
  constexpr int W = 2*C;
  constexpr int RPF = 256/W;
  int t = threadIdx.x;
  int c = t % W, r0 = t / W;
  float acc = 0.f;
  for(int r = blockIdx.x*RPF + r0; r < nblk; r += 64*RPF)
    acc += partials[(size_t)r*W + c];
  __shared__ float ls[256];
  ls[t] = acc;
  __syncthreads();
  if(t < W){
    float s = 0.f;
    #pragma unroll
    for(int k=0;k<RPF;k++) s += ls[k*W + t];
    red[blockIdx.x*W + t] = s;
  }
}

// ================= BN finalize + plain f32 weight prep (layer 2): Wp = sc.*W, cp = sh @ W ===========
template<int C>
__global__ __launch_bounds__(256) void k_bn_finprep2(const float* __restrict__ red,
                           const float* __restrict__ gw, const float* __restrict__ be,
                           float invN, const float* __restrict__ W,
                           float* __restrict__ Wp, float* __restrict__ cp){
  __shared__ float s0[C], s1[C], scf[C], shf[C];
  int t = threadIdx.x;
  if(t < 2*C){
    float s = 0.f;
    for(int r=0;r<64;r++) s += red[r*2*C + t];
    if(t < C) s0[t] = s; else s1[t-C] = s;
  }
  __syncthreads();
  if(t < C){
    float m = s0[t]*invN;
    float var = fmaxf(s1[t]*invN - m*m, 0.f);
    float inv = rsqrtf(var + EPSV);
    float sc = gw[t]*inv;
    scf[t] = sc;
    shf[t] = be[t] - m*sc;
  }
  __syncthreads();
  for(int i=t; i<C*64; i+=256){
    int k = i >> 6;
    Wp[i] = scf[k]*W[i];
  }
  if(t < 64){
    float s = 0.f;
    for(int k=0;k<C;k++) s += shf[k]*W[k*64 + t];
    cp[t] = s;
  }
}

// ================= BN finalize + frag-packed bf16 weight prep (layer 3) =================
// wf frag packing: lane l supplies (col=ct*16+(l&15)), elems k=(l>>4)*8+e+32*half
__global__ __launch_bounds__(256) void k_bn_finprep3(const float* __restrict__ red,
                           const float* __restrict__ gw, const float* __restrict__ be,
                           float invN, const float* __restrict__ W,
                           ushort_t* __restrict__ wf, float* __restrict__ cp){
  __shared__ float s0[64], s1[64], scf[64], shf[64];
  int t = threadIdx.x;
  if(t < 128){
    float s = 0.f;
    for(int r=0;r<64;r++) s += red[r*128 + t];
    if(t < 64) s0[t] = s; else s1[t-64] = s;
  }
  __syncthreads();
  if(t < 64){
    float m = s0[t]*invN;
    float var = fmaxf(s1[t]*invN - m*m, 0.f);
    float inv = rsqrtf(var + EPSV);
    float sc = gw[t]*inv;
    scf[t] = sc;
    shf[t] = be[t] - m*sc;
  }
  __syncthreads();
  int total = 4*2*64*8;    // ct(4) x half(2) x lane(64) x elem(8)
  for(int idx=t; idx<total; idx+=256){
    int e = idx & 7;
    int l = (idx>>3) & 63;
    int slot = idx>>9;             // ct*2 + half
    int ct = slot>>1, half = slot&1;
    int k = (l>>4)*8 + e + half*32;
    int col = ct*16 + (l&15);
    wf[idx] = (ushort_t)f2bf(scf[k]*W[k*64 + col]);
  }
  if(t < 64){
    float s = 0.f;
    for(int k=0;k<64;k++) s += shf[k]*W[k*64 + t];
    cp[t] = s;
  }
}

// ================= layer-2 fused: gather Q1 (16-wide) + VALU GEMM + tanh + stats =================
__global__ __launch_bounds__(256) void k_l2fused(const int* __restrict__ rp,
    const int* __restrict__ csr_src, const float* __restrict__ dis,
    const float* __restrict__ sdis, const ushort_t* __restrict__ Q1,
    const float* __restrict__ Wp, const float* __restrict__ cp,
    const float* __restrict__ bias, int N, ushort_t* __restrict__ Q2,
    float* __restrict__ partials){
  __shared__ __align__(16) float Wl[16*64];
  __shared__ float cpl[64], bl[64];
  int t = threadIdx.x;
  for(int i=t; i<16*64; i+=256) Wl[i] = Wp[i];
  if(t < 64){ cpl[t] = cp[t]; bl[t] = bias[t]; }
  __syncthreads();

  int idx = blockIdx.x*256 + t;
  int n = idx >> 3, g = t & 7;
  int half = g & 1, eo = g >> 1;
  bool valid = (n < N);
  float M8[8];
  #pragma unroll
  for(int j=0;j<8;j++) M8[j]=0.f;

  if(valid){
    int beg = rp[n], end = rp[n+1];
    if(eo == 0){
      uint4 u = *(const uint4*)(Q1 + (size_t)n*16 + half*8);
      M8[0]+=BF_LO(u.x); M8[1]+=BF_HI(u.x); M8[2]+=BF_LO(u.y); M8[3]+=BF_HI(u.y);
      M8[4]+=BF_LO(u.z); M8[5]+=BF_HI(u.z); M8[6]+=BF_LO(u.w); M8[7]+=BF_HI(u.w);
    }
    for(int j=beg+eo; j<end; j+=4){
      int s = csr_src[j];
      uint4 u = *(const uint4*)(Q1 + (size_t)s*16 + half*8);
      M8[0]+=BF_LO(u.x); M8[1]+=BF_HI(u.x); M8[2]+=BF_LO(u.y); M8[3]+=BF_HI(u.y);
      M8[4]+=BF_LO(u.z); M8[5]+=BF_HI(u.z); M8[6]+=BF_LO(u.w); M8[7]+=BF_HI(u.w);
    }
  }
  #pragma unroll
  for(int j=0;j<8;j++){
    float m = M8[j];
    m += __shfl_xor(m, 2, 64);
    m += __shfl_xor(m, 4, 64);
    M8[j] = m;
  }
  float M16[16];
  #pragma unroll
  for(int j=0;j<8;j++){
    float o = __shfl_xor(M8[j], 1, 64);
    M16[j]   = (half==0) ? M8[j] : o;
    M16[8+j] = (half==0) ? o     : M8[j];
  }

  float v[8];
  #pragma unroll
  for(int j=0;j<8;j++) v[j]=0.f;
  if(valid){
    float d = dis[n];
    float sg = sdis[n] + d;
    int c0 = g*8;
    float acc[8];
    #pragma unroll
    for(int j=0;j<8;j++) acc[j] = cpl[c0+j]*sg;
    #pragma unroll
    for(int k=0;k<16;k++){
      float m = M16[k];
      float4 w0 = *(const float4*)&Wl[k*64 + c0];
      float4 w1 = *(const float4*)&Wl[k*64 + c0 + 4];
      acc[0]+=m*w0.x; acc[1]+=m*w0.y; acc[2]+=m*w0.z; acc[3]+=m*w0.w;
      acc[4]+=m*w1.x; acc[5]+=m*w1.y; acc[6]+=m*w1.z; acc[7]+=m*w1.w;
    }
    #pragma unroll
    for(int j=0;j<8;j++) v[j] = tanhf(d*acc[j] + bl[c0+j]);
    uint4 o;
    o.x = f2bf(v[0]*d) | (f2bf(v[1]*d)<<16);
    o.y = f2bf(v[2]*d) | (f2bf(v[3]*d)<<16);
    o.z = f2bf(v[4]*d) | (f2bf(v[5]*d)<<16);
    o.w = f2bf(v[6]*d) | (f2bf(v[7]*d)<<16);
    *(uint4*)(Q2 + (size_t)n*64 + c0) = o;
  }

  // BN stats over h2 (v), C=64, GP=8
  int lane = t & 63, wid = t >> 6;
  __shared__ float redS[4][8][8], redQ[4][8][8];
  #pragma unroll
  for(int j=0;j<8;j++){
    float s = v[j], q = v[j]*v[j];
    #pragma unroll
    for(int off=32; off>=8; off>>=1){
      s += __shfl_down(s, off, 64);
      q += __shfl_down(q, off, 64);
    }
    if(lane < 8){ redS[wid][lane][j] = s; redQ[wid][lane][j] = q; }
  }
  __syncthreads();
  if(t < 64){
    int gg = t>>3, j = t&7;
    float S = redS[0][gg][j]+redS[1][gg][j]+redS[2][gg][j]+redS[3][gg][j];
    float Q = redQ[0][gg][j]+redQ[1][gg][j]+redQ[2][gg][j]+redQ[3][gg][j];
    partials[(size_t)blockIdx.x*128 + t]      = S;
    partials[(size_t)blockIdx.x*128 + 64 + t] = Q;
  }
}

// ================= layer-3 gather: M3 = bf16(Q2[n] + sum Q2[s]) (no GEMM, no LDS) =================
__global__ __launch_bounds__(256) void k_gather3(const int* __restrict__ rp,
    const int* __restrict__ csr_src, const ushort_t* __restrict__ Q2,
    int N, ushort_t* __restrict__ M3){
  int t = threadIdx.x;
  int idx = blockIdx.x*256 + t;
  int n = idx >> 3, g = t & 7;
  if(n >= N) return;
  int beg = rp[n], end = rp[n+1];
  uint4 u = *(const uint4*)(Q2 + (size_t)n*64 + g*8);   // self
  float a0 = BF_LO(u.x), a1 = BF_HI(u.x), a2 = BF_LO(u.y), a3 = BF_HI(u.y);
  float a4 = BF_LO(u.z), a5 = BF_HI(u.z), a6 = BF_LO(u.w), a7 = BF_HI(u.w);
  float b0=0.f,b1=0.f,b2=0.f,b3=0.f,b4=0.f,b5=0.f,b6=0.f,b7=0.f;
  int j = beg;
  for(; j+1 < end; j += 2){
    int s0 = csr_src[j], s1 = csr_src[j+1];
    uint4 u0 = *(const uint4*)(Q2 + (size_t)s0*64 + g*8);
    uint4 u1 = *(const uint4*)(Q2 + (size_t)s1*64 + g*8);
    a0 += BF_LO(u0.x); a1 += BF_HI(u0.x); a2 += BF_LO(u0.y); a3 += BF_HI(u0.y);
    a4 += BF_LO(u0.z); a5 += BF_HI(u0.z); a6 += BF_LO(u0.w); a7 += BF_HI(u0.w);
    b0 += BF_LO(u1.x); b1 += BF_HI(u1.x); b2 += BF_LO(u1.y); b3 += BF_HI(u1.y);
    b4 += BF_LO(u1.z); b5 += BF_HI(u1.z); b6 += BF_LO(u1.w); b7 += BF_HI(u1.w);
  }
  if(j < end){
    int s0 = csr_src[j];
    uint4 u0 = *(const uint4*)(Q2 + (size_t)s0*64 + g*8);
    a0 += BF_LO(u0.x); a1 += BF_HI(u0.x); a2 += BF_LO(u0.y); a3 += BF_HI(u0.y);
    a4 += BF_LO(u0.z); a5 += BF_HI(u0.z); a6 += BF_LO(u0.w); a7 += BF_HI(u0.w);
  }
  uint4 o;
  o.x = f2bf(a0+b0) | (f2bf(a1+b1)<<16);
  o.y = f2bf(a2+b2) | (f2bf(a3+b3)<<16);
  o.z = f2bf(a4+b4) | (f2bf(a5+b5)<<16);
  o.w = f2bf(a6+b6) | (f2bf(a7+b7)<<16);
  *(uint4*)(M3 + (size_t)n*64 + g*8) = o;
}

// ================= MFMA head: y[n] = tanh(dis*(M3@W3' + sg*cp) + b3) . Wc =================
__global__ __launch_bounds__(256) void k_mfma_head(const ushort_t* __restrict__ M3,
                                                   const ushort_t* __restrict__ wf,
                                                   const float* __restrict__ cp,
                                                   const float* __restrict__ dis,
                                                   const float* __restrict__ sdis,
                                                   const float* __restrict__ b3,
                                                   const float* __restrict__ Wc,
                                                   int N, float* __restrict__ y){
  int t = threadIdx.x, wid = t>>6, l = t&63;
  int r0 = blockIdx.x*128 + wid*32;

  bf16x8 bfr[4][2];
  #pragma unroll
  for(int ct=0; ct<4; ct++)
    #pragma unroll
    for(int h=0; h<2; h++)
      bfr[ct][h] = *(const bf16x8*)(wf + ((size_t)(ct*2+h)*64 + l)*8);

  bf16x8 af[2][2];
  #pragma unroll
  for(int rt=0; rt<2; rt++){
    int arow = r0 + rt*16 + (l&15);
    int k0 = (l>>4)*8;
    #pragma unroll
    for(int h=0; h<2; h++){
      if(arow < N) af[rt][h] = *(const bf16x8*)(M3 + (size_t)arow*64 + k0 + h*32);
      else         af[rt][h] = (bf16x8){0,0,0,0,0,0,0,0};
    }
  }

  f32x4 acc[2][4];
  #pragma unroll
  for(int rt=0; rt<2; rt++)
    #pragma unroll
    for(int ct=0; ct<4; ct++)
      acc[rt][ct] = (f32x4){0.f,0.f,0.f,0.f};

  #pragma unroll
  for(int rt=0; rt<2; rt++)
    #pragma unroll
    for(int ct=0; ct<4; ct++)
      #pragma unroll
      for(int h=0; h<2; h++)
        acc[rt][ct] = __builtin_amdgcn_mfma_f32_16x16x32_bf16(af[rt][h], bfr[ct][h], acc[rt][ct], 0, 0, 0);

  // per-lane constants for its 4 columns (col = ct*16 + (l&15))
  float cpc[4], blc[4], wcc[4];
  #pragma unroll
  for(int ct=0; ct<4; ct++){
    int col = ct*16 + (l&15);
    cpc[ct] = cp[col]; blc[ct] = b3[col]; wcc[ct] = Wc[col];
  }

  // C/D: col = lane&15 (+16*ct), row = (lane>>4)*4 + reg (+16*rt)
  #pragma unroll
  for(int rt=0; rt<2; rt++){
    int rbase = r0 + rt*16 + (l>>4)*4;
    #pragma unroll
    for(int reg=0; reg<4; reg++){
      int row = rbase + reg;
      bool ok = (row < N);
      float d  = ok ? dis[row] : 0.f;
      float sg = ok ? (sdis[row] + d) : 0.f;
      float s = 0.f;
      #pragma unroll
      for(int ct=0; ct<4; ct++){
        float h = tanhf(d*(acc[rt][ct][reg] + sg*cpc[ct]) + blc[ct]);
        s += h*wcc[ct];
      }
      // reduce across the 16 lanes sharing this row
      s += __shfl_xor(s, 1, 64);
      s += __shfl_xor(s, 2, 64);
      s += __shfl_xor(s, 4, 64);
      s += __shfl_xor(s, 8, 64);
      if(ok && (l&15)==0) y[row] = s;
    }
  }
}

// ================= pool: out[g] = mean(y over graph rows) + bc =================
__global__ __launch_bounds__(64) void k_pool2(const float* __restrict__ y,
                                              const int* __restrict__ batch, int N,
                                              const float* __restrict__ bc,
                                              float* __restrict__ out){
  int gId = blockIdx.x;
  int t = threadIdx.x;
  int lo=0, hi=N;
  while(lo<hi){ int mid=(lo+hi)>>1; if(batch[mid] < gId) lo=mid+1; else hi=mid; }
  int start = lo;
  lo=start; hi=N;
  while(lo<hi){ int mid=(lo+hi)>>1; if(batch[mid] < gId+1) lo=mid+1; else hi=mid; }
  int end = lo;

  float s = 0.f;
  for(int r = start+t; r < end; r += 64) s += y[r];
  #pragma unroll
  for(int o=32; o>0; o>>=1) s += __shfl_down(s, o, 64);
  if(t == 0){
    float cnt = (float)(end - start);
    out[gId] = s / fmaxf(cnt, 1.0f) + bc[0];
  }
}

// ================= host launch =================
extern "C" void kernel_launch(void* const* d_in, const int* in_sizes, int n_in,
                              void* d_out, int out_size, void* d_ws, size_t ws_size,
                              hipStream_t stream) {
  const float* x     = (const float*)d_in[0];
  const int*   ei    = (const int*)d_in[1];
  const int*   batch = (const int*)d_in[2];
  const float* W1 = (const float*)d_in[3];
  const float* b1 = (const float*)d_in[4];
  const float* g1 = (const float*)d_in[5];
  const float* be1= (const float*)d_in[6];
  const float* W2 = (const float*)d_in[7];
  const float* b2 = (const float*)d_in[8];
  const float* g2 = (const float*)d_in[9];
  const float* be2= (const float*)d_in[10];
  const float* W3 = (const float*)d_in[11];
  const float* b3 = (const float*)d_in[12];
  const float* Wc = (const float*)d_in[13];
  const float* bc = (const float*)d_in[14];

  int N = in_sizes[2];
  int E = in_sizes[1] / 2;
  int G = out_size;
  const int* srcp = ei;
  const int* dstp = ei + E;
  float* out = (float*)d_out;

  auto cdiv = [](long long a, long long b){ return (int)((a+b-1)/b); };
  auto al16 = [](size_t s){ return (s + 15) & ~(size_t)15; };
  int nbuk  = cdiv(N, NPB);
  int chunk = cdiv(E, EB);
  int L     = nbuk * EB;
  int nbL   = cdiv(L, 1024);
  int nblk16 = cdiv((long long)N*2, 256);
  int nblk64 = cdiv((long long)N*8, 256);

  char* w = (char*)d_ws;
  ushort_t* Q1       = (ushort_t*)w; w += al16((size_t)N*16*2);
  ushort_t* P1       = (ushort_t*)w; w += al16((size_t)N*16*2);
  ushort_t* Q2       = (ushort_t*)w; w += al16((size_t)N*64*2);
  ushort_t* M3       = (ushort_t*)w; w += al16((size_t)N*64*2);
  float*    dis      = (float*)w;    w += al16((size_t)N*4);
  float*    sdis     = (float*)w;    w += al16((size_t)N*4);
  float*    yv       = (float*)w;    w += al16((size_t)N*4);
  int*      row_ptr  = (int*)w;      w += al16((size_t)(N+1)*4);
  int*      csr_src  = (int*)w;      w += al16((size_t)E*4);
  unsigned* epk      = (unsigned*)w; w += al16((size_t)E*4);
  int*      cnt      = (int*)w;      w += al16((size_t)L*4);
  int*      scan_loc = (int*)w;      w += al16((size_t)L*4);
  int*      scan_blk = (int*)w;      w += al16(1024*4);
  float*    partials = (float*)w;    w += al16((size_t)nblk64*128*4);
  float*    red      = (float*)w;    w += al16(64*128*4);
  float*    Wp       = (float*)w;    w += al16(16*64*4);
  float*    cp       = (float*)w;    w += al16(64*4);
  ushort_t* wf       = (ushort_t*)w; w += al16(8*64*8*2);

  // ---- CSR build ----
  k_csr_count<<<EB,256,0,stream>>>(dstp, E, chunk, nbuk, cnt);
  k_scan_local<<<nbL,1024,0,stream>>>(cnt, L, scan_loc, scan_blk);
  k_scan_sums<<<1,1024,0,stream>>>(scan_blk, nbL, row_ptr + N);
  k_csr_scatter<<<EB,256,0,stream>>>(srcp, dstp, scan_loc, scan_blk, E, chunk, nbuk, epk);
  k_csr_final<<<nbuk,256,0,stream>>>(epk, scan_loc, scan_blk, nbuk, N, E, row_ptr, dis, csr_src);

  // ---- Layer 1: 32 -> 16 ----
  k_gemm1<<<cdiv(N,256),256,0,stream>>>(x, W1, dis, N, P1);
  k_gather1<<<nblk16,256,0,stream>>>(row_ptr, csr_src, dis, P1, b1, N, Q1, sdis, partials);
  k_bn_red<16><<<64,256,0,stream>>>(partials, nblk16, red);
  k_bn_finprep2<16><<<1,256,0,stream>>>(red, g1, be1, 1.0f/N, W2, Wp, cp);

  // ---- Layer 2: fused gather(16-wide) + VALU GEMM + stats ----
  k_l2fused<<<nblk64,256,0,stream>>>(row_ptr, csr_src, dis, sdis, Q1, Wp, cp, b2, N, Q2, partials);
  k_bn_red<64><<<64,256,0,stream>>>(partials, nblk64, red);
  k_bn_finprep3<<<1,256,0,stream>>>(red, g2, be2, 1.0f/N, W3, wf, cp);

  // ---- Layer 3: gather (64-wide) -> MFMA GEMM + fused head ----
  k_gather3<<<nblk64,256,0,stream>>>(row_ptr, csr_src, Q2, N, M3);
  k_mfma_head<<<cdiv(N,128),256,0,stream>>>(M3, wf, cp, dis, sdis, b3, Wc, N, yv);

  // ---- Pool ----
  k_pool2<<<G,64,0,stream>>>(yv, batch, N, bc, out);
}

// Round 12
// 187.219 us; speedup vs baseline: 1.2055x; 1.0789x over previous
//
#include <hip/hip_runtime.h>

#define EPSV 1e-5f
#define EB 512            // edge-chunk blocks for counting-sort passes
#define NPB 256           // nodes per bucket (bucket = dst >> 8)
#define NBUK_MAX 512      // supports N up to 131072

typedef __attribute__((ext_vector_type(8))) short bf16x8;
typedef __attribute__((ext_vector_type(4))) float f32x4;
typedef unsigned short ushort_t;

// ---- f32 -> bf16 round-to-nearest-even ----
__device__ inline unsigned f2bf(float f){
  unsigned u = __float_as_uint(f);
  u += 0x7fffu + ((u>>16)&1u);
  return u>>16;
}
#define BF_LO(u) __uint_as_float((u)<<16)
#define BF_HI(u) __uint_as_float((u)&0xffff0000u)

// ================= CSR build (two-level counting sort, no global atomics) =================
__global__ __launch_bounds__(256) void k_csr_count(const int* __restrict__ dst, int E, int chunk,
                                                   int nbuk, int* __restrict__ cnt){
  __shared__ int hist[NBUK_MAX];
  int t = threadIdx.x, b = blockIdx.x;
  for(int k=t; k<nbuk; k+=256) hist[k]=0;
  __syncthreads();
  int lo = b*chunk, hi = lo+chunk < E ? lo+chunk : E;
  for(int i=lo+t; i<hi; i+=256) atomicAdd(&hist[dst[i]>>8], 1);
  __syncthreads();
  for(int k=t; k<nbuk; k+=256) cnt[(size_t)k*EB + b] = hist[k];
}

__global__ __launch_bounds__(1024) void k_scan_local(const int* __restrict__ v_in, int L,
                                                     int* __restrict__ loc, int* __restrict__ blk){
  __shared__ int ps[1024];
  int t = threadIdx.x;
  int i = blockIdx.x*1024 + t;
  int v = (i < L) ? v_in[i] : 0;
  ps[t] = v;
  __syncthreads();
  for(int off=1; off<1024; off<<=1){
    int u = (t>=off) ? ps[t-off] : 0;
    __syncthreads();
    ps[t] += u;
    __syncthreads();
  }
  if(i < L) loc[i] = ps[t] - v;
  if(t == 1023) blk[blockIdx.x] = ps[t];
}

__global__ __launch_bounds__(1024) void k_scan_sums(int* __restrict__ blk, int nb,
                                                    int* __restrict__ totalOut){
  __shared__ int ps[1024];
  int t = threadIdx.x;
  int v = (t < nb) ? blk[t] : 0;
  ps[t] = v;
  __syncthreads();
  for(int off=1; off<1024; off<<=1){
    int u = (t>=off) ? ps[t-off] : 0;
    __syncthreads();
    ps[t] += u;
    __syncthreads();
  }
  if(t < nb) blk[t] = ps[t] - v;
  if(t == 1023) *totalOut = ps[t];
}

__global__ __launch_bounds__(256) void k_csr_scatter(const int* __restrict__ src,
                                                     const int* __restrict__ dst,
                                                     const int* __restrict__ loc,
                                                     const int* __restrict__ blk,
                                                     int E, int chunk, int nbuk,
                                                     unsigned* __restrict__ epk){
  __shared__ int cur[NBUK_MAX];
  int t = threadIdx.x, b = blockIdx.x;
  for(int k=t; k<nbuk; k+=256){
    int i = k*EB + b;
    cur[k] = loc[i] + blk[i>>10];
  }
  __syncthreads();
  int lo = b*chunk, hi = lo+chunk < E ? lo+chunk : E;
  for(int i=lo+t; i<hi; i+=256){
    int d = dst[i];
    int p = atomicAdd(&cur[d>>8], 1);
    epk[p] = ((unsigned)src[i]<<8) | (unsigned)(d & 255);
  }
}

__global__ __launch_bounds__(256) void k_csr_final(const unsigned* __restrict__ epk,
                                                   const int* __restrict__ loc,
                                                   const int* __restrict__ blk,
                                                   int nbuk, int N, int E,
                                                   int* __restrict__ rp, float* __restrict__ dis,
                                                   int* __restrict__ csr_src){
  __shared__ int hist[NPB], ps[NPB], cur[NPB];
  int t = threadIdx.x, k = blockIdx.x;
  int i0 = k*EB;
  int base = loc[i0] + blk[i0>>10];
  int next;
  if(k+1 < nbuk){ int i1 = (k+1)*EB; next = loc[i1] + blk[i1>>10]; }
  else next = E;
  int cntk = next - base;
  int node0 = k*NPB;
  hist[t] = 0;
  __syncthreads();
  for(int i=t; i<cntk; i+=256) atomicAdd(&hist[(int)(epk[base+i] & 255u)], 1);
  __syncthreads();
  int deg = hist[t];
  ps[t] = deg;
  __syncthreads();
  for(int off=1; off<256; off<<=1){
    int u = (t>=off) ? ps[t-off] : 0;
    __syncthreads();
    ps[t] += u;
    __syncthreads();
  }
  int lb = ps[t] - deg;
  int n = node0 + t;
  if(n < N){
    rp[n]  = base + lb;
    dis[n] = rsqrtf((float)deg + 1.0f);
  }
  cur[t] = base + lb;
  __syncthreads();
  for(int i=t; i<cntk; i+=256){
    unsigned e = epk[base+i];
    int p = atomicAdd(&cur[(int)(e & 255u)], 1);
    csr_src[p] = (int)(e >> 8);
  }
  if(k == nbuk-1 && t == 0) rp[N] = E;
}

// ================= layer-1 GEMM (f32 VALU): P1 = bf16((x @ W1) * dis[row]) =================
__global__ __launch_bounds__(256) void k_gemm1(const float* __restrict__ x,
                                               const float* __restrict__ W,
                                               const float* __restrict__ dis,
                                               int N, ushort_t* __restrict__ P1){
  __shared__ __align__(16) float Ws[32*16];
  int t = threadIdx.x;
  for(int i=t; i<32*16; i+=256) Ws[i] = W[i];
  __syncthreads();
  int row = blockIdx.x*256 + t;
  if(row >= N) return;
  const float4* xr = (const float4*)(x + (size_t)row*32);
  float acc[16];
  #pragma unroll
  for(int j=0;j<16;j++) acc[j]=0.f;
  #pragma unroll
  for(int k4=0;k4<8;k4++){
    float4 v = xr[k4];
    float vv[4] = {v.x, v.y, v.z, v.w};
    #pragma unroll
    for(int kk=0;kk<4;kk++){
      float h = vv[kk];
      const float* wr = &Ws[(k4*4+kk)*16];
      #pragma unroll
      for(int j=0;j<16;j++) acc[j] += h*wr[j];
    }
  }
  float d = dis[row];
  unsigned q[8];
  #pragma unroll
  for(int j=0;j<8;j++)
    q[j] = f2bf(acc[2*j]*d) | (f2bf(acc[2*j+1]*d)<<16);
  uint4* o = (uint4*)(P1 + (size_t)row*16);
  o[0] = make_uint4(q[0],q[1],q[2],q[3]);
  o[1] = make_uint4(q[4],q[5],q[6],q[7]);
}

// ================= layer-1 gather: h1 = tanh(dis*(P1[n]+sum P1[s]) + b1) =================
// writes Q1 = bf16(h1 * dis), sdis[n] = sum dis[s], BN stats over h1
__global__ __launch_bounds__(256) void k_gather1(const int* __restrict__ rp,
    const int* __restrict__ csr_src,
    const float* __restrict__ dis, const ushort_t* __restrict__ P1,
    const float* __restrict__ bias, int N, ushort_t* __restrict__ Q1,
    float* __restrict__ sdis, float* __restrict__ partials){
  int t = threadIdx.x;
  int idx = blockIdx.x*256 + t;
  int n = idx >> 1, g = t & 1;
  float v[8];
  #pragma unroll
  for(int j=0;j<8;j++) v[j]=0.f;

  if(n < N){
    int beg = rp[n], end = rp[n+1];
    uint4 u = *(const uint4*)(P1 + (size_t)n*16 + g*8);
    float a0 = BF_LO(u.x), a1 = BF_HI(u.x), a2 = BF_LO(u.y), a3 = BF_HI(u.y);
    float a4 = BF_LO(u.z), a5 = BF_HI(u.z), a6 = BF_LO(u.w), a7 = BF_HI(u.w);
    float b0=0.f,b1=0.f,b2=0.f,b3=0.f,b4=0.f,b5=0.f,b6=0.f,b7=0.f;
    float sd = 0.f;
    int j = beg;
    for(; j+1 < end; j += 2){
      int s0 = csr_src[j], s1 = csr_src[j+1];
      uint4 u0 = *(const uint4*)(P1 + (size_t)s0*16 + g*8);
      uint4 u1 = *(const uint4*)(P1 + (size_t)s1*16 + g*8);
      if(g==0) sd += dis[s0] + dis[s1];
      a0 += BF_LO(u0.x); a1 += BF_HI(u0.x); a2 += BF_LO(u0.y); a3 += BF_HI(u0.y);
      a4 += BF_LO(u0.z); a5 += BF_HI(u0.z); a6 += BF_LO(u0.w); a7 += BF_HI(u0.w);
      b0 += BF_LO(u1.x); b1 += BF_HI(u1.x); b2 += BF_LO(u1.y); b3 += BF_HI(u1.y);
      b4 += BF_LO(u1.z); b5 += BF_HI(u1.z); b6 += BF_LO(u1.w); b7 += BF_HI(u1.w);
    }
    if(j < end){
      int s0 = csr_src[j];
      uint4 u0 = *(const uint4*)(P1 + (size_t)s0*16 + g*8);
      if(g==0) sd += dis[s0];
      a0 += BF_LO(u0.x); a1 += BF_HI(u0.x); a2 += BF_LO(u0.y); a3 += BF_HI(u0.y);
      a4 += BF_LO(u0.z); a5 += BF_HI(u0.z); a6 += BF_LO(u0.w); a7 += BF_HI(u0.w);
    }
    float d = dis[n];
    float4 bb0 = *(const float4*)(bias + g*8);
    float4 bb1 = *(const float4*)(bias + g*8 + 4);
    v[0] = tanhf((a0+b0)*d + bb0.x); v[1] = tanhf((a1+b1)*d + bb0.y);
    v[2] = tanhf((a2+b2)*d + bb0.z); v[3] = tanhf((a3+b3)*d + bb0.w);
    v[4] = tanhf((a4+b4)*d + bb1.x); v[5] = tanhf((a5+b5)*d + bb1.y);
    v[6] = tanhf((a6+b6)*d + bb1.z); v[7] = tanhf((a7+b7)*d + bb1.w);
    uint4 o;
    o.x = f2bf(v[0]*d) | (f2bf(v[1]*d)<<16);
    o.y = f2bf(v[2]*d) | (f2bf(v[3]*d)<<16);
    o.z = f2bf(v[4]*d) | (f2bf(v[5]*d)<<16);
    o.w = f2bf(v[6]*d) | (f2bf(v[7]*d)<<16);
    *(uint4*)(Q1 + (size_t)n*16 + g*8) = o;
    if(g==0) sdis[n] = sd;
  }

  // BN stats over h1 (v), C=16, GP=2
  int lane = t & 63, wid = t >> 6;
  __shared__ float redS[4][2][8], redQ[4][2][8];
  #pragma unroll
  for(int j=0;j<8;j++){
    float s = v[j], q = v[j]*v[j];
    #pragma unroll
    for(int off=32; off>=2; off>>=1){
      s += __shfl_down(s, off, 64);
      q += __shfl_down(q, off, 64);
    }
    if(lane < 2){ redS[wid][lane][j] = s; redQ[wid][lane][j] = q; }
  }
  __syncthreads();
  if(t < 16){
    int gg = t>>3, j = t&7;
    float S = redS[0][gg][j]+redS[1][gg][j]+redS[2][gg][j]+redS[3][gg][j];
    float Q = redQ[0][gg][j]+redQ[1][gg][j]+redQ[2][gg][j]+redQ[3][gg][j];
    partials[(size_t)blockIdx.x*32 + t]      = S;
    partials[(size_t)blockIdx.x*32 + 16 + t] = Q;
  }
}

// ================= BN reduce stage 1 =================
template<int C>
__global__ __launch_bounds__(256) void k_bn_red(const float* __restrict__ partials, int nblk,
                                                float* __restrict__ red){
  constexpr int W = 2*C;
  constexpr int RPF = 256/W;
  int t = threadIdx.x;
  int c = t % W, r0 = t / W;
  float acc = 0.f;
  for(int r = blockIdx.x*RPF + r0; r < nblk; r += 64*RPF)
    acc += partials[(size_t)r*W + c];
  __shared__ float ls[256];
  ls[t] = acc;
  __syncthreads();
  if(t < W){
    float s = 0.f;
    #pragma unroll
    for(int k=0;k<RPF;k++) s += ls[k*W + t];
    red[blockIdx.x*W + t] = s;
  }
}

// ================= BN1 finalize + frag-packed bf16 W2' (K padded 16->32) =================
// wf frag packing: lane l supplies (col=ct*16+(l&15)), elems k=(l>>4)*8+e; zero for k>=16
__global__ __launch_bounds__(256) void k_bn_finprep2b(const float* __restrict__ red,
                           const float* __restrict__ gw, const float* __restrict__ be,
                           float invN, const float* __restrict__ W,
                           ushort_t* __restrict__ wf, float* __restrict__ cp){
  __shared__ float s0[16], s1[16], scf[16], shf[16];
  int t = threadIdx.x;
  if(t < 32){
    float s = 0.f;
    for(int r=0;r<64;r++) s += red[r*32 + t];
    if(t < 16) s0[t] = s; else s1[t-16] = s;
  }
  __syncthreads();
  if(t < 16){
    float m = s0[t]*invN;
    float var = fmaxf(s1[t]*invN - m*m, 0.f);
    float inv = rsqrtf(var + EPSV);
    float sc = gw[t]*inv;
    scf[t] = sc;
    shf[t] = be[t] - m*sc;
  }
  __syncthreads();
  int total = 4*64*8;    // ct(4) x lane(64) x elem(8), single K=32 slab
  for(int idx=t; idx<total; idx+=256){
    int e = idx & 7;
    int l = (idx>>3) & 63;
    int ct = idx>>9;
    int k = (l>>4)*8 + e;
    int col = ct*16 + (l&15);
    float v = (k < 16) ? scf[k]*W[k*64 + col] : 0.f;
    wf[idx] = (ushort_t)f2bf(v);
  }
  if(t < 64){
    float s = 0.f;
    for(int k=0;k<16;k++) s += shf[k]*W[k*64 + t];
    cp[t] = s;
  }
}

// ================= BN2 finalize + frag-packed bf16 W3' (K=64) =================
__global__ __launch_bounds__(256) void k_bn_finprep3(const float* __restrict__ red,
                           const float* __restrict__ gw, const float* __restrict__ be,
                           float invN, const float* __restrict__ W,
                           ushort_t* __restrict__ wf, float* __restrict__ cp){
  __shared__ float s0[64], s1[64], scf[64], shf[64];
  int t = threadIdx.x;
  if(t < 128){
    float s = 0.f;
    for(int r=0;r<64;r++) s += red[r*128 + t];
    if(t < 64) s0[t] = s; else s1[t-64] = s;
  }
  __syncthreads();
  if(t < 64){
    float m = s0[t]*invN;
    float var = fmaxf(s1[t]*invN - m*m, 0.f);
    float inv = rsqrtf(var + EPSV);
    float sc = gw[t]*inv;
    scf[t] = sc;
    shf[t] = be[t] - m*sc;
  }
  __syncthreads();
  int total = 4*2*64*8;    // ct(4) x half(2) x lane(64) x elem(8)
  for(int idx=t; idx<total; idx+=256){
    int e = idx & 7;
    int l = (idx>>3) & 63;
    int slot = idx>>9;             // ct*2 + half
    int ct = slot>>1, half = slot&1;
    int k = (l>>4)*8 + e + half*32;
    int col = ct*16 + (l&15);
    wf[idx] = (ushort_t)f2bf(scf[k]*W[k*64 + col]);
  }
  if(t < 64){
    float s = 0.f;
    for(int k=0;k<64;k++) s += shf[k]*W[k*64 + t];
    cp[t] = s;
  }
}

// ================= layer-2 gather (16-wide): M2 = bf16(Q1[n] + sum Q1[s]) =================
__global__ __launch_bounds__(256) void k_gather2(const int* __restrict__ rp,
    const int* __restrict__ csr_src, const ushort_t* __restrict__ Q1,
    int N, ushort_t* __restrict__ M2){
  int t = threadIdx.x;
  int idx = blockIdx.x*256 + t;
  int n = idx >> 1, g = t & 1;
  if(n >= N) return;
  int beg = rp[n], end = rp[n+1];
  uint4 u = *(const uint4*)(Q1 + (size_t)n*16 + g*8);   // self
  float a0 = BF_LO(u.x), a1 = BF_HI(u.x), a2 = BF_LO(u.y), a3 = BF_HI(u.y);
  float a4 = BF_LO(u.z), a5 = BF_HI(u.z), a6 = BF_LO(u.w), a7 = BF_HI(u.w);
  float b0=0.f,b1=0.f,b2=0.f,b3=0.f,b4=0.f,b5=0.f,b6=0.f,b7=0.f;
  int j = beg;
  for(; j+1 < end; j += 2){
    int s0 = csr_src[j], s1 = csr_src[j+1];
    uint4 u0 = *(const uint4*)(Q1 + (size_t)s0*16 + g*8);
    uint4 u1 = *(const uint4*)(Q1 + (size_t)s1*16 + g*8);
    a0 += BF_LO(u0.x); a1 += BF_HI(u0.x); a2 += BF_LO(u0.y); a3 += BF_HI(u0.y);
    a4 += BF_LO(u0.z); a5 += BF_HI(u0.z); a6 += BF_LO(u0.w); a7 += BF_HI(u0.w);
    b0 += BF_LO(u1.x); b1 += BF_HI(u1.x); b2 += BF_LO(u1.y); b3 += BF_HI(u1.y);
    b4 += BF_LO(u1.z); b5 += BF_HI(u1.z); b6 += BF_LO(u1.w); b7 += BF_HI(u1.w);
  }
  if(j < end){
    int s0 = csr_src[j];
    uint4 u0 = *(const uint4*)(Q1 + (size_t)s0*16 + g*8);
    a0 += BF_LO(u0.x); a1 += BF_HI(u0.x); a2 += BF_LO(u0.y); a3 += BF_HI(u0.y);
    a4 += BF_LO(u0.z); a5 += BF_HI(u0.z); a6 += BF_LO(u0.w); a7 += BF_HI(u0.w);
  }
  uint4 o;
  o.x = f2bf(a0+b0) | (f2bf(a1+b1)<<16);
  o.y = f2bf(a2+b2) | (f2bf(a3+b3)<<16);
  o.z = f2bf(a4+b4) | (f2bf(a5+b5)<<16);
  o.w = f2bf(a6+b6) | (f2bf(a7+b7)<<16);
  *(uint4*)(M2 + (size_t)n*16 + g*8) = o;
}

// ================= layer-2 MFMA: h2 = tanh(d*(M2@W2' + sg*cp) + b2); Q2 = bf16(h2*d) + stats ======
__global__ __launch_bounds__(256) void k_mfma2(const ushort_t* __restrict__ M2,
                                               const ushort_t* __restrict__ wf,
                                               const float* __restrict__ cp,
                                               const float* __restrict__ dis,
                                               const float* __restrict__ sdis,
                                               const float* __restrict__ b2,
                                               int N, ushort_t* __restrict__ Q2,
                                               float* __restrict__ partials){
  int t = threadIdx.x, wid = t>>6, l = t&63;
  int r0 = blockIdx.x*128 + wid*32;

  bf16x8 bfr[4];
  #pragma unroll
  for(int ct=0; ct<4; ct++)
    bfr[ct] = *(const bf16x8*)(wf + ((size_t)ct*64 + l)*8);

  bf16x8 af[2];
  #pragma unroll
  for(int rt=0; rt<2; rt++){
    int arow = r0 + rt*16 + (l&15);
    int k0 = (l>>4)*8;
    if(arow < N && k0 < 16) af[rt] = *(const bf16x8*)(M2 + (size_t)arow*16 + k0);
    else                    af[rt] = (bf16x8){0,0,0,0,0,0,0,0};
  }

  f32x4 acc[2][4];
  #pragma unroll
  for(int rt=0; rt<2; rt++)
    #pragma unroll
    for(int ct=0; ct<4; ct++)
      acc[rt][ct] = (f32x4){0.f,0.f,0.f,0.f};

  #pragma unroll
  for(int rt=0; rt<2; rt++)
    #pragma unroll
    for(int ct=0; ct<4; ct++)
      acc[rt][ct] = __builtin_amdgcn_mfma_f32_16x16x32_bf16(af[rt], bfr[ct], acc[rt][ct], 0, 0, 0);

  float cpc[4], blc[4];
  #pragma unroll
  for(int ct=0; ct<4; ct++){
    int col = ct*16 + (l&15);
    cpc[ct] = cp[col]; blc[ct] = b2[col];
  }

  float S4[4] = {0.f,0.f,0.f,0.f}, Q4[4] = {0.f,0.f,0.f,0.f};
  // C/D: col = ct*16 + (lane&15), row = r0 + rt*16 + (lane>>4)*4 + reg
  #pragma unroll
  for(int rt=0; rt<2; rt++){
    int rbase = r0 + rt*16 + (l>>4)*4;
    #pragma unroll
    for(int reg=0; reg<4; reg++){
      int row = rbase + reg;
      if(row < N){
        float d = dis[row];
        float sg = sdis[row] + d;
        #pragma unroll
        for(int ct=0; ct<4; ct++){
          float h = tanhf(d*(acc[rt][ct][reg] + sg*cpc[ct]) + blc[ct]);
          Q2[(size_t)row*64 + ct*16 + (l&15)] = (ushort_t)f2bf(h*d);
          S4[ct] += h; Q4[ct] += h*h;
        }
      }
    }
  }
  // reduce across the 4 lanes sharing each col (lane bits 4,5)
  #pragma unroll
  for(int ct=0; ct<4; ct++){
    S4[ct] += __shfl_xor(S4[ct], 16, 64);
    S4[ct] += __shfl_xor(S4[ct], 32, 64);
    Q4[ct] += __shfl_xor(Q4[ct], 16, 64);
    Q4[ct] += __shfl_xor(Q4[ct], 32, 64);
  }
  __shared__ float wsm[4][64], wqm[4][64];
  if(l < 16){
    #pragma unroll
    for(int ct=0; ct<4; ct++){
      wsm[wid][ct*16 + l] = S4[ct];
      wqm[wid][ct*16 + l] = Q4[ct];
    }
  }
  __syncthreads();
  if(t < 64){
    float S = wsm[0][t]+wsm[1][t]+wsm[2][t]+wsm[3][t];
    float Q = wqm[0][t]+wqm[1][t]+wqm[2][t]+wqm[3][t];
    partials[(size_t)blockIdx.x*128 + t]      = S;
    partials[(size_t)blockIdx.x*128 + 64 + t] = Q;
  }
}

// ================= layer-3 gather: M3 = bf16(Q2[n] + sum Q2[s]) =================
__global__ __launch_bounds__(256) void k_gather3(const int* __restrict__ rp,
    const int* __restrict__ csr_src, const ushort_t* __restrict__ Q2,
    int N, ushort_t* __restrict__ M3){
  int t = threadIdx.x;
  int idx = blockIdx.x*256 + t;
  int n = idx >> 3, g = t & 7;
  if(n >= N) return;
  int beg = rp[n], end = rp[n+1];
  uint4 u = *(const uint4*)(Q2 + (size_t)n*64 + g*8);   // self
  float a0 = BF_LO(u.x), a1 = BF_HI(u.x), a2 = BF_LO(u.y), a3 = BF_HI(u.y);
  float a4 = BF_LO(u.z), a5 = BF_HI(u.z), a6 = BF_LO(u.w), a7 = BF_HI(u.w);
  float b0=0.f,b1=0.f,b2=0.f,b3=0.f,b4=0.f,b5=0.f,b6=0.f,b7=0.f;
  int j = beg;
  for(; j+1 < end; j += 2){
    int s0 = csr_src[j], s1 = csr_src[j+1];
    uint4 u0 = *(const uint4*)(Q2 + (size_t)s0*64 + g*8);
    uint4 u1 = *(const uint4*)(Q2 + (size_t)s1*64 + g*8);
    a0 += BF_LO(u0.x); a1 += BF_HI(u0.x); a2 += BF_LO(u0.y); a3 += BF_HI(u0.y);
    a4 += BF_LO(u0.z); a5 += BF_HI(u0.z); a6 += BF_LO(u0.w); a7 += BF_HI(u0.w);
    b0 += BF_LO(u1.x); b1 += BF_HI(u1.x); b2 += BF_LO(u1.y); b3 += BF_HI(u1.y);
    b4 += BF_LO(u1.z); b5 += BF_HI(u1.z); b6 += BF_LO(u1.w); b7 += BF_HI(u1.w);
  }
  if(j < end){
    int s0 = csr_src[j];
    uint4 u0 = *(const uint4*)(Q2 + (size_t)s0*64 + g*8);
    a0 += BF_LO(u0.x); a1 += BF_HI(u0.x); a2 += BF_LO(u0.y); a3 += BF_HI(u0.y);
    a4 += BF_LO(u0.z); a5 += BF_HI(u0.z); a6 += BF_LO(u0.w); a7 += BF_HI(u0.w);
  }
  uint4 o;
  o.x = f2bf(a0+b0) | (f2bf(a1+b1)<<16);
  o.y = f2bf(a2+b2) | (f2bf(a3+b3)<<16);
  o.z = f2bf(a4+b4) | (f2bf(a5+b5)<<16);
  o.w = f2bf(a6+b6) | (f2bf(a7+b7)<<16);
  *(uint4*)(M3 + (size_t)n*64 + g*8) = o;
}

// ================= MFMA head: y[n] = tanh(dis*(M3@W3' + sg*cp) + b3) . Wc =================
__global__ __launch_bounds__(256) void k_mfma_head(const ushort_t* __restrict__ M3,
                                                   const ushort_t* __restrict__ wf,
                                                   const float* __restrict__ cp,
                                                   const float* __restrict__ dis,
                                                   const float* __restrict__ sdis,
                                                   const float* __restrict__ b3,
                                                   const float* __restrict__ Wc,
                                                   int N, float* __restrict__ y){
  int t = threadIdx.x, wid = t>>6, l = t&63;
  int r0 = blockIdx.x*128 + wid*32;

  bf16x8 bfr[4][2];
  #pragma unroll
  for(int ct=0; ct<4; ct++)
    #pragma unroll
    for(int h=0; h<2; h++)
      bfr[ct][h] = *(const bf16x8*)(wf + ((size_t)(ct*2+h)*64 + l)*8);

  bf16x8 af[2][2];
  #pragma unroll
  for(int rt=0; rt<2; rt++){
    int arow = r0 + rt*16 + (l&15);
    int k0 = (l>>4)*8;
    #pragma unroll
    for(int h=0; h<2; h++){
      if(arow < N) af[rt][h] = *(const bf16x8*)(M3 + (size_t)arow*64 + k0 + h*32);
      else         af[rt][h] = (bf16x8){0,0,0,0,0,0,0,0};
    }
  }

  f32x4 acc[2][4];
  #pragma unroll
  for(int rt=0; rt<2; rt++)
    #pragma unroll
    for(int ct=0; ct<4; ct++)
      acc[rt][ct] = (f32x4){0.f,0.f,0.f,0.f};

  #pragma unroll
  for(int rt=0; rt<2; rt++)
    #pragma unroll
    for(int ct=0; ct<4; ct++)
      #pragma unroll
      for(int h=0; h<2; h++)
        acc[rt][ct] = __builtin_amdgcn_mfma_f32_16x16x32_bf16(af[rt][h], bfr[ct][h], acc[rt][ct], 0, 0, 0);

  float cpc[4], blc[4], wcc[4];
  #pragma unroll
  for(int ct=0; ct<4; ct++){
    int col = ct*16 + (l&15);
    cpc[ct] = cp[col]; blc[ct] = b3[col]; wcc[ct] = Wc[col];
  }

  #pragma unroll
  for(int rt=0; rt<2; rt++){
    int rbase = r0 + rt*16 + (l>>4)*4;
    #pragma unroll
    for(int reg=0; reg<4; reg++){
      int row = rbase + reg;
      bool ok = (row < N);
      float d  = ok ? dis[row] : 0.f;
      float sg = ok ? (sdis[row] + d) : 0.f;
      float s = 0.f;
      #pragma unroll
      for(int ct=0; ct<4; ct++){
        float h = tanhf(d*(acc[rt][ct][reg] + sg*cpc[ct]) + blc[ct]);
        s += h*wcc[ct];
      }
      s += __shfl_xor(s, 1, 64);
      s += __shfl_xor(s, 2, 64);
      s += __shfl_xor(s, 4, 64);
      s += __shfl_xor(s, 8, 64);
      if(ok && (l&15)==0) y[row] = s;
    }
  }
}

// ================= pool: out[g] = mean(y over graph rows) + bc =================
__global__ __launch_bounds__(64) void k_pool2(const float* __restrict__ y,
                                              const int* __restrict__ batch, int N,
                                              const float* __restrict__ bc,
                                              float* __restrict__ out){
  int gId = blockIdx.x;
  int t = threadIdx.x;
  int lo=0, hi=N;
  while(lo<hi){ int mid=(lo+hi)>>1; if(batch[mid] < gId) lo=mid+1; else hi=mid; }
  int start = lo;
  lo=start; hi=N;
  while(lo<hi){ int mid=(lo+hi)>>1; if(batch[mid] < gId+1) lo=mid+1; else hi=mid; }
  int end = lo;

  float s = 0.f;
  for(int r = start+t; r < end; r += 64) s += y[r];
  #pragma unroll
  for(int o=32; o>0; o>>=1) s += __shfl_down(s, o, 64);
  if(t == 0){
    float cnt = (float)(end - start);
    out[gId] = s / fmaxf(cnt, 1.0f) + bc[0];
  }
}

// ================= host launch =================
extern "C" void kernel_launch(void* const* d_in, const int* in_sizes, int n_in,
                              void* d_out, int out_size, void* d_ws, size_t ws_size,
                              hipStream_t stream) {
  const float* x     = (const float*)d_in[0];
  const int*   ei    = (const int*)d_in[1];
  const int*   batch = (const int*)d_in[2];
  const float* W1 = (const float*)d_in[3];
  const float* b1 = (const float*)d_in[4];
  const float* g1 = (const float*)d_in[5];
  const float* be1= (const float*)d_in[6];
  const float* W2 = (const float*)d_in[7];
  const float* b2 = (const float*)d_in[8];
  const float* g2 = (const float*)d_in[9];
  const float* be2= (const float*)d_in[10];
  const float* W3 = (const float*)d_in[11];
  const float* b3 = (const float*)d_in[12];
  const float* Wc = (const float*)d_in[13];
  const float* bc = (const float*)d_in[14];

  int N = in_sizes[2];
  int E = in_sizes[1] / 2;
  int G = out_size;
  const int* srcp = ei;
  const int* dstp = ei + E;
  float* out = (float*)d_out;

  auto cdiv = [](long long a, long long b){ return (int)((a+b-1)/b); };
  auto al16 = [](size_t s){ return (s + 15) & ~(size_t)15; };
  int nbuk  = cdiv(N, NPB);
  int chunk = cdiv(E, EB);
  int L     = nbuk * EB;
  int nbL   = cdiv(L, 1024);
  int nblk16 = cdiv((long long)N*2, 256);
  int nblk64 = cdiv((long long)N*8, 256);
  int nblkM  = cdiv(N, 128);

  char* w = (char*)d_ws;
  ushort_t* Q1       = (ushort_t*)w; w += al16((size_t)N*16*2);
  ushort_t* P1       = (ushort_t*)w; w += al16((size_t)N*16*2);
  ushort_t* M2       = (ushort_t*)w; w += al16((size_t)N*16*2);
  ushort_t* Q2       = (ushort_t*)w; w += al16((size_t)N*64*2);
  ushort_t* M3       = (ushort_t*)w; w += al16((size_t)N*64*2);
  float*    dis      = (float*)w;    w += al16((size_t)N*4);
  float*    sdis     = (float*)w;    w += al16((size_t)N*4);
  float*    yv       = (float*)w;    w += al16((size_t)N*4);
  int*      row_ptr  = (int*)w;      w += al16((size_t)(N+1)*4);
  int*      csr_src  = (int*)w;      w += al16((size_t)E*4);
  unsigned* epk      = (unsigned*)w; w += al16((size_t)E*4);
  int*      cnt      = (int*)w;      w += al16((size_t)L*4);
  int*      scan_loc = (int*)w;      w += al16((size_t)L*4);
  int*      scan_blk = (int*)w;      w += al16(1024*4);
  float*    partials = (float*)w;    w += al16((size_t)nblk64*128*4);
  float*    red      = (float*)w;    w += al16(64*128*4);
  float*    cp       = (float*)w;    w += al16(64*4);
  ushort_t* wf       = (ushort_t*)w; w += al16(8*64*8*2);

  // ---- CSR build ----
  k_csr_count<<<EB,256,0,stream>>>(dstp, E, chunk, nbuk, cnt);
  k_scan_local<<<nbL,1024,0,stream>>>(cnt, L, scan_loc, scan_blk);
  k_scan_sums<<<1,1024,0,stream>>>(scan_blk, nbL, row_ptr + N);
  k_csr_scatter<<<EB,256,0,stream>>>(srcp, dstp, scan_loc, scan_blk, E, chunk, nbuk, epk);
  k_csr_final<<<nbuk,256,0,stream>>>(epk, scan_loc, scan_blk, nbuk, N, E, row_ptr, dis, csr_src);

  // ---- Layer 1: 32 -> 16 ----
  k_gemm1<<<cdiv(N,256),256,0,stream>>>(x, W1, dis, N, P1);
  k_gather1<<<nblk16,256,0,stream>>>(row_ptr, csr_src, dis, P1, b1, N, Q1, sdis, partials);
  k_bn_red<16><<<64,256,0,stream>>>(partials, nblk16, red);
  k_bn_finprep2b<<<1,256,0,stream>>>(red, g1, be1, 1.0f/N, W2, wf, cp);

  // ---- Layer 2: gather(16-wide) -> MFMA GEMM (stats fused) ----
  k_gather2<<<nblk16,256,0,stream>>>(row_ptr, csr_src, Q1, N, M2);
  k_mfma2<<<nblkM,256,0,stream>>>(M2, wf, cp, dis, sdis, b2, N, Q2, partials);
  k_bn_red<64><<<64,256,0,stream>>>(partials, nblkM, red);
  k_bn_finprep3<<<1,256,0,stream>>>(red, g2, be2, 1.0f/N, W3, wf, cp);

  // ---- Layer 3: gather (64-wide) -> MFMA GEMM + fused head ----
  k_gather3<<<nblk64,256,0,stream>>>(row_ptr, csr_src, Q2, N, M3);
  k_mfma_head<<<cdiv(N,128),256,0,stream>>>(M3, wf, cp, dis, sdis, b3, Wc, N, yv);

  // ---- Pool ----
  k_pool2<<<G,64,0,stream>>>(yv, batch, N, bc, out);
}

// Round 13
// 176.118 us; speedup vs baseline: 1.2815x; 1.0630x over previous
//
#include <hip/hip_runtime.h>

#define EPSV 1e-5f
#define EB 512            // edge-chunk blocks for counting-sort passes
#define NPB 256           // nodes per bucket (bucket = dst >> 8)
#define NBUK_MAX 512      // supports N up to 131072

typedef __attribute__((ext_vector_type(8))) short bf16x8;
typedef __attribute__((ext_vector_type(4))) float f32x4;
typedef unsigned short ushort_t;

// ---- f32 -> bf16 round-to-nearest-even ----
__device__ inline unsigned f2bf(float f){
  unsigned u = __float_as_uint(f);
  u += 0x7fffu + ((u>>16)&1u);
  return u>>16;
}
#define BF_LO(u) __uint_as_float((u)<<16)
#define BF_HI(u) __uint_as_float((u)&0xffff0000u)

// ================= CSR build (two-level counting sort, no global atomics) =================
// chunk is a multiple of 4; edge reads vectorized as int4.
__global__ __launch_bounds__(256) void k_csr_count(const int* __restrict__ dst, int E, int chunk,
                                                   int nbuk, int* __restrict__ cnt){
  __shared__ int hist[NBUK_MAX];
  int t = threadIdx.x, b = blockIdx.x;
  for(int k=t; k<nbuk; k+=256) hist[k]=0;
  __syncthreads();
  int lo = b*chunk, hi = lo+chunk < E ? lo+chunk : E;
  for(int i=lo+t*4; i+3<hi; i+=1024){
    int4 d4 = *(const int4*)(dst + i);
    atomicAdd(&hist[d4.x>>8], 1); atomicAdd(&hist[d4.y>>8], 1);
    atomicAdd(&hist[d4.z>>8], 1); atomicAdd(&hist[d4.w>>8], 1);
  }
  int rem = lo + ((hi - lo) & ~3);
  for(int i=rem+t; i<hi; i+=256) atomicAdd(&hist[dst[i]>>8], 1);
  __syncthreads();
  for(int k=t; k<nbuk; k+=256) cnt[(size_t)k*EB + b] = hist[k];
}

__global__ __launch_bounds__(1024) void k_scan_local(const int* __restrict__ v_in, int L,
                                                     int* __restrict__ loc, int* __restrict__ blk){
  __shared__ int ps[1024];
  int t = threadIdx.x;
  int i = blockIdx.x*1024 + t;
  int v = (i < L) ? v_in[i] : 0;
  ps[t] = v;
  __syncthreads();
  for(int off=1; off<1024; off<<=1){
    int u = (t>=off) ? ps[t-off] : 0;
    __syncthreads();
    ps[t] += u;
    __syncthreads();
  }
  if(i < L) loc[i] = ps[t] - v;
  if(t == 1023) blk[blockIdx.x] = ps[t];
}

__global__ __launch_bounds__(1024) void k_scan_sums(int* __restrict__ blk, int nb,
                                                    int* __restrict__ totalOut){
  __shared__ int ps[1024];
  int t = threadIdx.x;
  int v = (t < nb) ? blk[t] : 0;
  ps[t] = v;
  __syncthreads();
  for(int off=1; off<1024; off<<=1){
    int u = (t>=off) ? ps[t-off] : 0;
    __syncthreads();
    ps[t] += u;
    __syncthreads();
  }
  if(t < nb) blk[t] = ps[t] - v;
  if(t == 1023) *totalOut = ps[t];
}

__global__ __launch_bounds__(256) void k_csr_scatter(const int* __restrict__ src,
                                                     const int* __restrict__ dst,
                                                     const int* __restrict__ loc,
                                                     const int* __restrict__ blk,
                                                     int E, int chunk, int nbuk,
                                                     unsigned* __restrict__ epk){
  __shared__ int cur[NBUK_MAX];
  int t = threadIdx.x, b = blockIdx.x;
  for(int k=t; k<nbuk; k+=256){
    int i = k*EB + b;
    cur[k] = loc[i] + blk[i>>10];
  }
  __syncthreads();
  int lo = b*chunk, hi = lo+chunk < E ? lo+chunk : E;
  for(int i=lo+t*4; i+3<hi; i+=1024){
    int4 s4 = *(const int4*)(src + i);
    int4 d4 = *(const int4*)(dst + i);
    int p0 = atomicAdd(&cur[d4.x>>8], 1);
    epk[p0] = ((unsigned)s4.x<<8) | (unsigned)(d4.x & 255);
    int p1 = atomicAdd(&cur[d4.y>>8], 1);
    epk[p1] = ((unsigned)s4.y<<8) | (unsigned)(d4.y & 255);
    int p2 = atomicAdd(&cur[d4.z>>8], 1);
    epk[p2] = ((unsigned)s4.z<<8) | (unsigned)(d4.z & 255);
    int p3 = atomicAdd(&cur[d4.w>>8], 1);
    epk[p3] = ((unsigned)s4.w<<8) | (unsigned)(d4.w & 255);
  }
  int rem = lo + ((hi - lo) & ~3);
  for(int i=rem+t; i<hi; i+=256){
    int d = dst[i];
    int p = atomicAdd(&cur[d>>8], 1);
    epk[p] = ((unsigned)src[i]<<8) | (unsigned)(d & 255);
  }
}

__global__ __launch_bounds__(256) void k_csr_final(const unsigned* __restrict__ epk,
                                                   const int* __restrict__ loc,
                                                   const int* __restrict__ blk,
                                                   int nbuk, int N, int E,
                                                   int* __restrict__ rp, float* __restrict__ dis,
                                                   int* __restrict__ csr_src){
  __shared__ int hist[NPB], ps[NPB], cur[NPB];
  int t = threadIdx.x, k = blockIdx.x;
  int i0 = k*EB;
  int base = loc[i0] + blk[i0>>10];
  int next;
  if(k+1 < nbuk){ int i1 = (k+1)*EB; next = loc[i1] + blk[i1>>10]; }
  else next = E;
  int cntk = next - base;
  int node0 = k*NPB;
  hist[t] = 0;
  __syncthreads();
  for(int i=t; i<cntk; i+=256) atomicAdd(&hist[(int)(epk[base+i] & 255u)], 1);
  __syncthreads();
  int deg = hist[t];
  ps[t] = deg;
  __syncthreads();
  for(int off=1; off<256; off<<=1){
    int u = (t>=off) ? ps[t-off] : 0;
    __syncthreads();
    ps[t] += u;
    __syncthreads();
  }
  int lb = ps[t] - deg;
  int n = node0 + t;
  if(n < N){
    rp[n]  = base + lb;
    dis[n] = rsqrtf((float)deg + 1.0f);
  }
  cur[t] = base + lb;
  __syncthreads();
  for(int i=t; i<cntk; i+=256){
    unsigned e = epk[base+i];
    int p = atomicAdd(&cur[(int)(e & 255u)], 1);
    csr_src[p] = (int)(e >> 8);
  }
  if(k == nbuk-1 && t == 0) rp[N] = E;
}

// ================= layer-1 GEMM (f32 VALU): P1 = bf16((x @ W1) * dis[row]) =================
__global__ __launch_bounds__(256) void k_gemm1(const float* __restrict__ x,
                                               const float* __restrict__ W,
                                               const float* __restrict__ dis,
                                               int N, ushort_t* __restrict__ P1){
  __shared__ __align__(16) float Ws[32*16];
  int t = threadIdx.x;
  for(int i=t; i<32*16; i+=256) Ws[i] = W[i];
  __syncthreads();
  int row = blockIdx.x*256 + t;
  if(row >= N) return;
  const float4* xr = (const float4*)(x + (size_t)row*32);
  float acc[16];
  #pragma unroll
  for(int j=0;j<16;j++) acc[j]=0.f;
  #pragma unroll
  for(int k4=0;k4<8;k4++){
    float4 v = xr[k4];
    float vv[4] = {v.x, v.y, v.z, v.w};
    #pragma unroll
    for(int kk=0;kk<4;kk++){
      float h = vv[kk];
      const float* wr = &Ws[(k4*4+kk)*16];
      #pragma unroll
      for(int j=0;j<16;j++) acc[j] += h*wr[j];
    }
  }
  float d = dis[row];
  unsigned q[8];
  #pragma unroll
  for(int j=0;j<8;j++)
    q[j] = f2bf(acc[2*j]*d) | (f2bf(acc[2*j+1]*d)<<16);
  uint4* o = (uint4*)(P1 + (size_t)row*16);
  o[0] = make_uint4(q[0],q[1],q[2],q[3]);
  o[1] = make_uint4(q[4],q[5],q[6],q[7]);
}

// ================= layer-1 gather: h1 = tanh(dis*(P1[n]+sum P1[s]) + b1) =================
// 4 loads in flight, 2 accumulator sets. writes Q1 = bf16(h1*dis), sdis, BN stats.
__global__ __launch_bounds__(256) void k_gather1(const int* __restrict__ rp,
    const int* __restrict__ csr_src,
    const float* __restrict__ dis, const ushort_t* __restrict__ P1,
    const float* __restrict__ bias, int N, ushort_t* __restrict__ Q1,
    float* __restrict__ sdis, float* __restrict__ partials){
  int t = threadIdx.x;
  int idx = blockIdx.x*256 + t;
  int n = idx >> 1, g = t & 1;
  float v[8];
  #pragma unroll
  for(int j=0;j<8;j++) v[j]=0.f;

  if(n < N){
    int beg = rp[n], end = rp[n+1];
    const uint4* Pv = (const uint4*)P1;
    uint4 u = Pv[(size_t)n*2 + g];
    float a0 = BF_LO(u.x), a1 = BF_HI(u.x), a2 = BF_LO(u.y), a3 = BF_HI(u.y);
    float a4 = BF_LO(u.z), a5 = BF_HI(u.z), a6 = BF_LO(u.w), a7 = BF_HI(u.w);
    float b0=0.f,b1=0.f,b2=0.f,b3=0.f,b4=0.f,b5=0.f,b6=0.f,b7=0.f;
    float sd = 0.f;
    int j = beg;
    for(; j+3 < end; j += 4){
      int s0 = csr_src[j], s1 = csr_src[j+1], s2 = csr_src[j+2], s3 = csr_src[j+3];
      uint4 u0 = Pv[(size_t)s0*2 + g];
      uint4 u1 = Pv[(size_t)s1*2 + g];
      uint4 u2 = Pv[(size_t)s2*2 + g];
      uint4 u3 = Pv[(size_t)s3*2 + g];
      if(g==0) sd += (dis[s0] + dis[s1]) + (dis[s2] + dis[s3]);
      a0 += BF_LO(u0.x); a1 += BF_HI(u0.x); a2 += BF_LO(u0.y); a3 += BF_HI(u0.y);
      a4 += BF_LO(u0.z); a5 += BF_HI(u0.z); a6 += BF_LO(u0.w); a7 += BF_HI(u0.w);
      b0 += BF_LO(u1.x); b1 += BF_HI(u1.x); b2 += BF_LO(u1.y); b3 += BF_HI(u1.y);
      b4 += BF_LO(u1.z); b5 += BF_HI(u1.z); b6 += BF_LO(u1.w); b7 += BF_HI(u1.w);
      a0 += BF_LO(u2.x); a1 += BF_HI(u2.x); a2 += BF_LO(u2.y); a3 += BF_HI(u2.y);
      a4 += BF_LO(u2.z); a5 += BF_HI(u2.z); a6 += BF_LO(u2.w); a7 += BF_HI(u2.w);
      b0 += BF_LO(u3.x); b1 += BF_HI(u3.x); b2 += BF_LO(u3.y); b3 += BF_HI(u3.y);
      b4 += BF_LO(u3.z); b5 += BF_HI(u3.z); b6 += BF_LO(u3.w); b7 += BF_HI(u3.w);
    }
    for(; j < end; ++j){
      int s0 = csr_src[j];
      uint4 u0 = Pv[(size_t)s0*2 + g];
      if(g==0) sd += dis[s0];
      a0 += BF_LO(u0.x); a1 += BF_HI(u0.x); a2 += BF_LO(u0.y); a3 += BF_HI(u0.y);
      a4 += BF_LO(u0.z); a5 += BF_HI(u0.z); a6 += BF_LO(u0.w); a7 += BF_HI(u0.w);
    }
    float d = dis[n];
    float4 bb0 = *(const float4*)(bias + g*8);
    float4 bb1 = *(const float4*)(bias + g*8 + 4);
    v[0] = tanhf((a0+b0)*d + bb0.x); v[1] = tanhf((a1+b1)*d + bb0.y);
    v[2] = tanhf((a2+b2)*d + bb0.z); v[3] = tanhf((a3+b3)*d + bb0.w);
    v[4] = tanhf((a4+b4)*d + bb1.x); v[5] = tanhf((a5+b5)*d + bb1.y);
    v[6] = tanhf((a6+b6)*d + bb1.z); v[7] = tanhf((a7+b7)*d + bb1.w);
    uint4 o;
    o.x = f2bf(v[0]*d) | (f2bf(v[1]*d)<<16);
    o.y = f2bf(v[2]*d) | (f2bf(v[3]*d)<<16);
    o.z = f2bf(v[4]*d) | (f2bf(v[5]*d)<<16);
    o.w = f2bf(v[6]*d) | (f2bf(v[7]*d)<<16);
    *(uint4*)(Q1 + (size_t)n*16 + g*8) = o;
    if(g==0) sdis[n] = sd;
  }

  // BN stats over h1 (v), C=16, GP=2
  int lane = t & 63, wid = t >> 6;
  __shared__ float redS[4][2][8], redQ[4][2][8];
  #pragma unroll
  for(int j=0;j<8;j++){
    float s = v[j], q = v[j]*v[j];
    #pragma unroll
    for(int off=32; off>=2; off>>=1){
      s += __shfl_down(s, off, 64);
      q += __shfl_down(q, off, 64);
    }
    if(lane < 2){ redS[wid][lane][j] = s; redQ[wid][lane][j] = q; }
  }
  __syncthreads();
  if(t < 16){
    int gg = t>>3, j = t&7;
    float S = redS[0][gg][j]+redS[1][gg][j]+redS[2][gg][j]+redS[3][gg][j];
    float Q = redQ[0][gg][j]+redQ[1][gg][j]+redQ[2][gg][j]+redQ[3][gg][j];
    partials[(size_t)blockIdx.x*32 + t]      = S;
    partials[(size_t)blockIdx.x*32 + 16 + t] = Q;
  }
}

// ================= BN reduce stage 1 =================
template<int C>
__global__ __launch_bounds__(256) void k_bn_red(const float* __restrict__ partials, int nblk,
                                                float* __restrict__ red){
  constexpr int W = 2*C;
  constexpr int RPF = 256/W;
  int t = threadIdx.x;
  int c = t % W, r0 = t / W;
  float acc = 0.f;
  for(int r = blockIdx.x*RPF + r0; r < nblk; r += 64*RPF)
    acc += partials[(size_t)r*W + c];
  __shared__ float ls[256];
  ls[t] = acc;
  __syncthreads();
  if(t < W){
    float s = 0.f;
    #pragma unroll
    for(int k=0;k<RPF;k++) s += ls[k*W + t];
    red[blockIdx.x*W + t] = s;
  }
}

// ================= BN1 finalize + frag-packed bf16 W2' (K padded 16->32) =================
__global__ __launch_bounds__(256) void k_bn_finprep2b(const float* __restrict__ red,
                           const float* __restrict__ gw, const float* __restrict__ be,
                           float invN, const float* __restrict__ W,
                           ushort_t* __restrict__ wf, float* __restrict__ cp){
  __shared__ float s0[16], s1[16], scf[16], shf[16];
  int t = threadIdx.x;
  if(t < 32){
    float s = 0.f;
    for(int r=0;r<64;r++) s += red[r*32 + t];
    if(t < 16) s0[t] = s; else s1[t-16] = s;
  }
  __syncthreads();
  if(t < 16){
    float m = s0[t]*invN;
    float var = fmaxf(s1[t]*invN - m*m, 0.f);
    float inv = rsqrtf(var + EPSV);
    float sc = gw[t]*inv;
    scf[t] = sc;
    shf[t] = be[t] - m*sc;
  }
  __syncthreads();
  int total = 4*64*8;
  for(int idx=t; idx<total; idx+=256){
    int e = idx & 7;
    int l = (idx>>3) & 63;
    int ct = idx>>9;
    int k = (l>>4)*8 + e;
    int col = ct*16 + (l&15);
    float v = (k < 16) ? scf[k]*W[k*64 + col] : 0.f;
    wf[idx] = (ushort_t)f2bf(v);
  }
  if(t < 64){
    float s = 0.f;
    for(int k=0;k<16;k++) s += shf[k]*W[k*64 + t];
    cp[t] = s;
  }
}

// ================= BN2 finalize + frag-packed bf16 W3' (K=64) =================
__global__ __launch_bounds__(256) void k_bn_finprep3(const float* __restrict__ red,
                           const float* __restrict__ gw, const float* __restrict__ be,
                           float invN, const float* __restrict__ W,
                           ushort_t* __restrict__ wf, float* __restrict__ cp){
  __shared__ float s0[64], s1[64], scf[64], shf[64];
  int t = threadIdx.x;
  if(t < 128){
    float s = 0.f;
    for(int r=0;r<64;r++) s += red[r*128 + t];
    if(t < 64) s0[t] = s; else s1[t-64] = s;
  }
  __syncthreads();
  if(t < 64){
    float m = s0[t]*invN;
    float var = fmaxf(s1[t]*invN - m*m, 0.f);
    float inv = rsqrtf(var + EPSV);
    float sc = gw[t]*inv;
    scf[t] = sc;
    shf[t] = be[t] - m*sc;
  }
  __syncthreads();
  int total = 4*2*64*8;
  for(int idx=t; idx<total; idx+=256){
    int e = idx & 7;
    int l = (idx>>3) & 63;
    int slot = idx>>9;
    int ct = slot>>1, half = slot&1;
    int k = (l>>4)*8 + e + half*32;
    int col = ct*16 + (l&15);
    wf[idx] = (ushort_t)f2bf(scf[k]*W[k*64 + col]);
  }
  if(t < 64){
    float s = 0.f;
    for(int k=0;k<64;k++) s += shf[k]*W[k*64 + t];
    cp[t] = s;
  }
}

// ================= layer-2 gather (16-wide, 4-deep MLP): M2 = bf16(Q1[n] + sum Q1[s]) ============
__global__ __launch_bounds__(256) void k_gather2(const int* __restrict__ rp,
    const int* __restrict__ csr_src, const ushort_t* __restrict__ Q1,
    int N, ushort_t* __restrict__ M2){
  int t = threadIdx.x;
  int idx = blockIdx.x*256 + t;
  int n = idx >> 1, g = t & 1;
  if(n >= N) return;
  int beg = rp[n], end = rp[n+1];
  const uint4* Pv = (const uint4*)Q1;
  uint4 u = Pv[(size_t)n*2 + g];
  float a0 = BF_LO(u.x), a1 = BF_HI(u.x), a2 = BF_LO(u.y), a3 = BF_HI(u.y);
  float a4 = BF_LO(u.z), a5 = BF_HI(u.z), a6 = BF_LO(u.w), a7 = BF_HI(u.w);
  float b0=0.f,b1=0.f,b2=0.f,b3=0.f,b4=0.f,b5=0.f,b6=0.f,b7=0.f;
  int j = beg;
  for(; j+3 < end; j += 4){
    int s0 = csr_src[j], s1 = csr_src[j+1], s2 = csr_src[j+2], s3 = csr_src[j+3];
    uint4 u0 = Pv[(size_t)s0*2 + g];
    uint4 u1 = Pv[(size_t)s1*2 + g];
    uint4 u2 = Pv[(size_t)s2*2 + g];
    uint4 u3 = Pv[(size_t)s3*2 + g];
    a0 += BF_LO(u0.x); a1 += BF_HI(u0.x); a2 += BF_LO(u0.y); a3 += BF_HI(u0.y);
    a4 += BF_LO(u0.z); a5 += BF_HI(u0.z); a6 += BF_LO(u0.w); a7 += BF_HI(u0.w);
    b0 += BF_LO(u1.x); b1 += BF_HI(u1.x); b2 += BF_LO(u1.y); b3 += BF_HI(u1.y);
    b4 += BF_LO(u1.z); b5 += BF_HI(u1.z); b6 += BF_LO(u1.w); b7 += BF_HI(u1.w);
    a0 += BF_LO(u2.x); a1 += BF_HI(u2.x); a2 += BF_LO(u2.y); a3 += BF_HI(u2.y);
    a4 += BF_LO(u2.z); a5 += BF_HI(u2.z); a6 += BF_LO(u2.w); a7 += BF_HI(u2.w);
    b0 += BF_LO(u3.x); b1 += BF_HI(u3.x); b2 += BF_LO(u3.y); b3 += BF_HI(u3.y);
    b4 += BF_LO(u3.z); b5 += BF_HI(u3.z); b6 += BF_LO(u3.w); b7 += BF_HI(u3.w);
  }
  for(; j < end; ++j){
    int s0 = csr_src[j];
    uint4 u0 = Pv[(size_t)s0*2 + g];
    a0 += BF_LO(u0.x); a1 += BF_HI(u0.x); a2 += BF_LO(u0.y); a3 += BF_HI(u0.y);
    a4 += BF_LO(u0.z); a5 += BF_HI(u0.z); a6 += BF_LO(u0.w); a7 += BF_HI(u0.w);
  }
  uint4 o;
  o.x = f2bf(a0+b0) | (f2bf(a1+b1)<<16);
  o.y = f2bf(a2+b2) | (f2bf(a3+b3)<<16);
  o.z = f2bf(a4+b4) | (f2bf(a5+b5)<<16);
  o.w = f2bf(a6+b6) | (f2bf(a7+b7)<<16);
  *(uint4*)(M2 + (size_t)n*16 + g*8) = o;
}

// ================= layer-2 MFMA: h2 = tanh(d*(M2@W2' + sg*cp) + b2); Q2 = bf16(h2*d) + stats ======
__global__ __launch_bounds__(256) void k_mfma2(const ushort_t* __restrict__ M2,
                                               const ushort_t* __restrict__ wf,
                                               const float* __restrict__ cp,
                                               const float* __restrict__ dis,
                                               const float* __restrict__ sdis,
                                               const float* __restrict__ b2,
                                               int N, ushort_t* __restrict__ Q2,
                                               float* __restrict__ partials){
  int t = threadIdx.x, wid = t>>6, l = t&63;
  int r0 = blockIdx.x*128 + wid*32;

  bf16x8 bfr[4];
  #pragma unroll
  for(int ct=0; ct<4; ct++)
    bfr[ct] = *(const bf16x8*)(wf + ((size_t)ct*64 + l)*8);

  bf16x8 af[2];
  #pragma unroll
  for(int rt=0; rt<2; rt++){
    int arow = r0 + rt*16 + (l&15);
    int k0 = (l>>4)*8;
    if(arow < N && k0 < 16) af[rt] = *(const bf16x8*)(M2 + (size_t)arow*16 + k0);
    else                    af[rt] = (bf16x8){0,0,0,0,0,0,0,0};
  }

  f32x4 acc[2][4];
  #pragma unroll
  for(int rt=0; rt<2; rt++)
    #pragma unroll
    for(int ct=0; ct<4; ct++)
      acc[rt][ct] = (f32x4){0.f,0.f,0.f,0.f};

  #pragma unroll
  for(int rt=0; rt<2; rt++)
    #pragma unroll
    for(int ct=0; ct<4; ct++)
      acc[rt][ct] = __builtin_amdgcn_mfma_f32_16x16x32_bf16(af[rt], bfr[ct], acc[rt][ct], 0, 0, 0);

  float cpc[4], blc[4];
  #pragma unroll
  for(int ct=0; ct<4; ct++){
    int col = ct*16 + (l&15);
    cpc[ct] = cp[col]; blc[ct] = b2[col];
  }

  float S4[4] = {0.f,0.f,0.f,0.f}, Q4[4] = {0.f,0.f,0.f,0.f};
  #pragma unroll
  for(int rt=0; rt<2; rt++){
    int rbase = r0 + rt*16 + (l>>4)*4;
    #pragma unroll
    for(int reg=0; reg<4; reg++){
      int row = rbase + reg;
      if(row < N){
        float d = dis[row];
        float sg = sdis[row] + d;
        #pragma unroll
        for(int ct=0; ct<4; ct++){
          float h = tanhf(d*(acc[rt][ct][reg] + sg*cpc[ct]) + blc[ct]);
          Q2[(size_t)row*64 + ct*16 + (l&15)] = (ushort_t)f2bf(h*d);
          S4[ct] += h; Q4[ct] += h*h;
        }
      }
    }
  }
  #pragma unroll
  for(int ct=0; ct<4; ct++){
    S4[ct] += __shfl_xor(S4[ct], 16, 64);
    S4[ct] += __shfl_xor(S4[ct], 32, 64);
    Q4[ct] += __shfl_xor(Q4[ct], 16, 64);
    Q4[ct] += __shfl_xor(Q4[ct], 32, 64);
  }
  __shared__ float wsm[4][64], wqm[4][64];
  if(l < 16){
    #pragma unroll
    for(int ct=0; ct<4; ct++){
      wsm[wid][ct*16 + l] = S4[ct];
      wqm[wid][ct*16 + l] = Q4[ct];
    }
  }
  __syncthreads();
  if(t < 64){
    float S = wsm[0][t]+wsm[1][t]+wsm[2][t]+wsm[3][t];
    float Q = wqm[0][t]+wqm[1][t]+wqm[2][t]+wqm[3][t];
    partials[(size_t)blockIdx.x*128 + t]      = S;
    partials[(size_t)blockIdx.x*128 + 64 + t] = Q;
  }
}

// ================= layer-3 gather (64-wide, 4-deep MLP): M3 = bf16(Q2[n] + sum Q2[s]) ============
__global__ __launch_bounds__(256) void k_gather3(const int* __restrict__ rp,
    const int* __restrict__ csr_src, const ushort_t* __restrict__ Q2,
    int N, ushort_t* __restrict__ M3){
  int t = threadIdx.x;
  int idx = blockIdx.x*256 + t;
  int n = idx >> 3, g = t & 7;
  if(n >= N) return;
  int beg = rp[n], end = rp[n+1];
  const uint4* Pv = (const uint4*)Q2;
  uint4 u = Pv[(size_t)n*8 + g];
  float a0 = BF_LO(u.x), a1 = BF_HI(u.x), a2 = BF_LO(u.y), a3 = BF_HI(u.y);
  float a4 = BF_LO(u.z), a5 = BF_HI(u.z), a6 = BF_LO(u.w), a7 = BF_HI(u.w);
  float b0=0.f,b1=0.f,b2=0.f,b3=0.f,b4=0.f,b5=0.f,b6=0.f,b7=0.f;
  int j = beg;
  for(; j+3 < end; j += 4){
    int s0 = csr_src[j], s1 = csr_src[j+1], s2 = csr_src[j+2], s3 = csr_src[j+3];
    uint4 u0 = Pv[(size_t)s0*8 + g];
    uint4 u1 = Pv[(size_t)s1*8 + g];
    uint4 u2 = Pv[(size_t)s2*8 + g];
    uint4 u3 = Pv[(size_t)s3*8 + g];
    a0 += BF_LO(u0.x); a1 += BF_HI(u0.x); a2 += BF_LO(u0.y); a3 += BF_HI(u0.y);
    a4 += BF_LO(u0.z); a5 += BF_HI(u0.z); a6 += BF_LO(u0.w); a7 += BF_HI(u0.w);
    b0 += BF_LO(u1.x); b1 += BF_HI(u1.x); b2 += BF_LO(u1.y); b3 += BF_HI(u1.y);
    b4 += BF_LO(u1.z); b5 += BF_HI(u1.z); b6 += BF_LO(u1.w); b7 += BF_HI(u1.w);
    a0 += BF_LO(u2.x); a1 += BF_HI(u2.x); a2 += BF_LO(u2.y); a3 += BF_HI(u2.y);
    a4 += BF_LO(u2.z); a5 += BF_HI(u2.z); a6 += BF_LO(u2.w); a7 += BF_HI(u2.w);
    b0 += BF_LO(u3.x); b1 += BF_HI(u3.x); b2 += BF_LO(u3.y); b3 += BF_HI(u3.y);
    b4 += BF_LO(u3.z); b5 += BF_HI(u3.z); b6 += BF_LO(u3.w); b7 += BF_HI(u3.w);
  }
  for(; j < end; ++j){
    int s0 = csr_src[j];
    uint4 u0 = Pv[(size_t)s0*8 + g];
    a0 += BF_LO(u0.x); a1 += BF_HI(u0.x); a2 += BF_LO(u0.y); a3 += BF_HI(u0.y);
    a4 += BF_LO(u0.z); a5 += BF_HI(u0.z); a6 += BF_LO(u0.w); a7 += BF_HI(u0.w);
  }
  uint4 o;
  o.x = f2bf(a0+b0) | (f2bf(a1+b1)<<16);
  o.y = f2bf(a2+b2) | (f2bf(a3+b3)<<16);
  o.z = f2bf(a4+b4) | (f2bf(a5+b5)<<16);
  o.w = f2bf(a6+b6) | (f2bf(a7+b7)<<16);
  *(uint4*)(M3 + (size_t)n*8*8 + g*8) = o;
}

// ================= MFMA head: y[n] = tanh(dis*(M3@W3' + sg*cp) + b3) . Wc =================
__global__ __launch_bounds__(256) void k_mfma_head(const ushort_t* __restrict__ M3,
                                                   const ushort_t* __restrict__ wf,
                                                   const float* __restrict__ cp,
                                                   const float* __restrict__ dis,
                                                   const float* __restrict__ sdis,
                                                   const float* __restrict__ b3,
                                                   const float* __restrict__ Wc,
                                                   int N, float* __restrict__ y){
  int t = threadIdx.x, wid = t>>6, l = t&63;
  int r0 = blockIdx.x*128 + wid*32;

  bf16x8 bfr[4][2];
  #pragma unroll
  for(int ct=0; ct<4; ct++)
    #pragma unroll
    for(int h=0; h<2; h++)
      bfr[ct][h] = *(const bf16x8*)(wf + ((size_t)(ct*2+h)*64 + l)*8);

  bf16x8 af[2][2];
  #pragma unroll
  for(int rt=0; rt<2; rt++){
    int arow = r0 + rt*16 + (l&15);
    int k0 = (l>>4)*8;
    #pragma unroll
    for(int h=0; h<2; h++){
      if(arow < N) af[rt][h] = *(const bf16x8*)(M3 + (size_t)arow*64 + k0 + h*32);
      else         af[rt][h] = (bf16x8){0,0,0,0,0,0,0,0};
    }
  }

  f32x4 acc[2][4];
  #pragma unroll
  for(int rt=0; rt<2; rt++)
    #pragma unroll
    for(int ct=0; ct<4; ct++)
      acc[rt][ct] = (f32x4){0.f,0.f,0.f,0.f};

  #pragma unroll
  for(int rt=0; rt<2; rt++)
    #pragma unroll
    for(int ct=0; ct<4; ct++)
      #pragma unroll
      for(int h=0; h<2; h++)
        acc[rt][ct] = __builtin_amdgcn_mfma_f32_16x16x32_bf16(af[rt][h], bfr[ct][h], acc[rt][ct], 0, 0, 0);

  float cpc[4], blc[4], wcc[4];
  #pragma unroll
  for(int ct=0; ct<4; ct++){
    int col = ct*16 + (l&15);
    cpc[ct] = cp[col]; blc[ct] = b3[col]; wcc[ct] = Wc[col];
  }

  #pragma unroll
  for(int rt=0; rt<2; rt++){
    int rbase = r0 + rt*16 + (l>>4)*4;
    #pragma unroll
    for(int reg=0; reg<4; reg++){
      int row = rbase + reg;
      bool ok = (row < N);
      float d  = ok ? dis[row] : 0.f;
      float sg = ok ? (sdis[row] + d) : 0.f;
      float s = 0.f;
      #pragma unroll
      for(int ct=0; ct<4; ct++){
        float h = tanhf(d*(acc[rt][ct][reg] + sg*cpc[ct]) + blc[ct]);
        s += h*wcc[ct];
      }
      s += __shfl_xor(s, 1, 64);
      s += __shfl_xor(s, 2, 64);
      s += __shfl_xor(s, 4, 64);
      s += __shfl_xor(s, 8, 64);
      if(ok && (l&15)==0) y[row] = s;
    }
  }
}

// ================= pool: out[g] = mean(y over graph rows) + bc =================
__global__ __launch_bounds__(64) void k_pool2(const float* __restrict__ y,
                                              const int* __restrict__ batch, int N,
                                              const float* __restrict__ bc,
                                              float* __restrict__ out){
  int gId = blockIdx.x;
  int t = threadIdx.x;
  int lo=0, hi=N;
  while(lo<hi){ int mid=(lo+hi)>>1; if(batch[mid] < gId) lo=mid+1; else hi=mid; }
  int start = lo;
  lo=start; hi=N;
  while(lo<hi){ int mid=(lo+hi)>>1; if(batch[mid] < gId+1) lo=mid+1; else hi=mid; }
  int end = lo;

  float s = 0.f;
  for(int r = start+t; r < end; r += 64) s += y[r];
  #pragma unroll
  for(int o=32; o>0; o>>=1) s += __shfl_down(s, o, 64);
  if(t == 0){
    float cnt = (float)(end - start);
    out[gId] = s / fmaxf(cnt, 1.0f) + bc[0];
  }
}

// ================= host launch =================
extern "C" void kernel_launch(void* const* d_in, const int* in_sizes, int n_in,
                              void* d_out, int out_size, void* d_ws, size_t ws_size,
                              hipStream_t stream) {
  const float* x     = (const float*)d_in[0];
  const int*   ei    = (const int*)d_in[1];
  const int*   batch = (const int*)d_in[2];
  const float* W1 = (const float*)d_in[3];
  const float* b1 = (const float*)d_in[4];
  const float* g1 = (const float*)d_in[5];
  const float* be1= (const float*)d_in[6];
  const float* W2 = (const float*)d_in[7];
  const float* b2 = (const float*)d_in[8];
  const float* g2 = (const float*)d_in[9];
  const float* be2= (const float*)d_in[10];
  const float* W3 = (const float*)d_in[11];
  const float* b3 = (const float*)d_in[12];
  const float* Wc = (const float*)d_in[13];
  const float* bc = (const float*)d_in[14];

  int N = in_sizes[2];
  int E = in_sizes[1] / 2;
  int G = out_size;
  const int* srcp = ei;
  const int* dstp = ei + E;
  float* out = (float*)d_out;

  auto cdiv = [](long long a, long long b){ return (int)((a+b-1)/b); };
  auto al16 = [](size_t s){ return (s + 15) & ~(size_t)15; };
  int nbuk  = cdiv(N, NPB);
  int chunk = 4*cdiv(E, (long long)EB*4);    // multiple of 4 for int4 edge reads
  int L     = nbuk * EB;
  int nbL   = cdiv(L, 1024);
  int nblk16 = cdiv((long long)N*2, 256);
  int nblk64 = cdiv((long long)N*8, 256);
  int nblkM  = cdiv(N, 128);

  char* w = (char*)d_ws;
  ushort_t* Q1       = (ushort_t*)w; w += al16((size_t)N*16*2);
  ushort_t* P1       = (ushort_t*)w; w += al16((size_t)N*16*2);
  ushort_t* M2       = (ushort_t*)w; w += al16((size_t)N*16*2);
  ushort_t* Q2       = (ushort_t*)w; w += al16((size_t)N*64*2);
  ushort_t* M3       = (ushort_t*)w; w += al16((size_t)N*64*2);
  float*    dis      = (float*)w;    w += al16((size_t)N*4);
  float*    sdis     = (float*)w;    w += al16((size_t)N*4);
  float*    yv       = (float*)w;    w += al16((size_t)N*4);
  int*      row_ptr  = (int*)w;      w += al16((size_t)(N+1)*4);
  int*      csr_src  = (int*)w;      w += al16((size_t)E*4);
  unsigned* epk      = (unsigned*)w; w += al16((size_t)E*4);
  int*      cnt      = (int*)w;      w += al16((size_t)L*4);
  int*      scan_loc = (int*)w;      w += al16((size_t)L*4);
  int*      scan_blk = (int*)w;      w += al16(1024*4);
  float*    partials = (float*)w;    w += al16((size_t)nblk64*128*4);
  float*    red      = (float*)w;    w += al16(64*128*4);
  float*    cp       = (float*)w;    w += al16(64*4);
  ushort_t* wf       = (ushort_t*)w; w += al16(8*64*8*2);

  // ---- CSR build ----
  k_csr_count<<<EB,256,0,stream>>>(dstp, E, chunk, nbuk, cnt);
  k_scan_local<<<nbL,1024,0,stream>>>(cnt, L, scan_loc, scan_blk);
  k_scan_sums<<<1,1024,0,stream>>>(scan_blk, nbL, row_ptr + N);
  k_csr_scatter<<<EB,256,0,stream>>>(srcp, dstp, scan_loc, scan_blk, E, chunk, nbuk, epk);
  k_csr_final<<<nbuk,256,0,stream>>>(epk, scan_loc, scan_blk, nbuk, N, E, row_ptr, dis, csr_src);

  // ---- Layer 1: 32 -> 16 ----
  k_gemm1<<<cdiv(N,256),256,0,stream>>>(x, W1, dis, N, P1);
  k_gather1<<<nblk16,256,0,stream>>>(row_ptr, csr_src, dis, P1, b1, N, Q1, sdis, partials);
  k_bn_red<16><<<64,256,0,stream>>>(partials, nblk16, red);
  k_bn_finprep2b<<<1,256,0,stream>>>(red, g1, be1, 1.0f/N, W2, wf, cp);

  // ---- Layer 2: gather(16-wide) -> MFMA GEMM (stats fused) ----
  k_gather2<<<nblk16,256,0,stream>>>(row_ptr, csr_src, Q1, N, M2);
  k_mfma2<<<nblkM,256,0,stream>>>(M2, wf, cp, dis, sdis, b2, N, Q2, partials);
  k_bn_red<64><<<64,256,0,stream>>>(partials, nblkM, red);
  k_bn_finprep3<<<1,256,0,stream>>>(red, g2, be2, 1.0f/N, W3, wf, cp);

  // ---- Layer 3: gather (64-wide) -> MFMA GEMM + fused head ----
  k_gather3<<<nblk64,256,0,stream>>>(row_ptr, csr_src, Q2, N, M3);
  k_mfma_head<<<cdiv(N,128),256,0,stream>>>(M3, wf, cp, dis, sdis, b3, Wc, N, yv);

  // ---- Pool ----
  k_pool2<<<G,64,0,stream>>>(yv, batch, N, bc, out);
}